// Round 1
// baseline (151.198 us; speedup 1.0000x reference)
//
#include <hip/hip_runtime.h>
#include <hip/hip_bf16.h>
#include <math.h>

#define NBOX  540      // total boxes per batch
#define NOBJ  135      // unique objects per batch
#define ZW    64
#define HIDN  512
#define NOUT  12288    // 3*64*64
#define OBJS  64
#define BATCH 4

// fused K1 block roles: [winner 256 | gemm1 540 | W2 cvt 1536]
#define ROLE_WIN   256
#define ROLE_G1    540
#define ROLE_CVT   ((NOUT / 64) * (HIDN / 64))   // 1536
#define PRE_BLOCKS (ROLE_WIN + ROLE_G1 + ROLE_CVT)

// workspace layout (bytes), 256-aligned
#define OFF_NROWS  0u          // int
#define OFF_USED   256u        // int[540]   -> 2416
#define OFF_REMAP  2560u       // int[540]   -> 4720
#define OFF_ROWOBJ 4864u       // int[640]   -> 7424
#define OFF_PXWIN  7680u       // int[65536] -> 269824
#define OFF_HBF    269824u     // ushort 640*512 = 655360 -> 925184
#define OFF_W2T    925184u     // ushort 12288*512 = 12582912 -> 13508096
#define OFF_DEC    13508096u   // float 640*12288 = 31457280 -> ~45 MB

typedef short  bf16x8 __attribute__((ext_vector_type(8)));
typedef float  f32x4  __attribute__((ext_vector_type(4)));

#define GLOAD_LDS16(gp, lp)                                                    \
  __builtin_amdgcn_global_load_lds(                                            \
      (const __attribute__((address_space(1))) void*)(gp),                     \
      (__attribute__((address_space(3))) void*)(lp), 16, 0, 0)

__device__ __forceinline__ unsigned short f2bf(float x) {
  __hip_bfloat16 h = __float2bfloat16(x);
  return *(unsigned short*)&h;
}

// ---------------------------------------------------------------------------
// K1: fused {painter visibility search | gemm1 | W2 cvt+T}
// Winner role: per 16x16 px tile, re-sort the batch's 135 depths (bitonic),
// walk boxes front-to-back with fp64 coverage predicates (identical math to
// the final composite), record per-pixel winning box and atomically build the
// compact list of visible objects for the pruned GEMM.
// ---------------------------------------------------------------------------
__global__ __launch_bounds__(256) void k_pre(
    const float* __restrict__ z_depth,   // B*135
    const float* __restrict__ z_where,   // B*540*4
    const int*   __restrict__ z_present, // B*540
    const float* __restrict__ Z,         // B*135*64 z_what
    const float* __restrict__ W1,        // 64*512
    const float* __restrict__ b1,        // 512
    const float* __restrict__ W2,        // 512*12288
    int* __restrict__ nrowsp,            // compact visible-row count (pre-zeroed)
    int* __restrict__ used,              // int[540] (pre-zeroed)
    int* __restrict__ remap,             // (b*135+obj) -> compact row
    int* __restrict__ rowobj,            // compact row -> (b*135+obj)
    int* __restrict__ pxwin,             // per-pixel winning box (orig id) or -1
    unsigned short* __restrict__ Hbf,    // 540*512 bf16
    unsigned short* __restrict__ W2T)    // 12288*512 bf16
{
  __shared__ unsigned long long keys[256];
  __shared__ float4 sw[NBOX];
  __shared__ unsigned char spres[NBOX];
  __shared__ float zs[ZW];
  __shared__ unsigned int T[64 * 36];

  const int bid = blockIdx.x;
  const int t   = threadIdx.x;

  if (bid < ROLE_WIN) {
    // ---- role 0: visibility search ----
#pragma clang fp contract(off)
    const int b    = bid >> 6;
    const int tile = bid & 63;
    const int y = (tile >> 3) * 16 + (t >> 4);
    const int x = (tile & 7) * 16 + (t & 15);

    unsigned long long key = ~0ull;
    if (t < NOBJ) {
      unsigned u = __float_as_uint(z_depth[b * NOBJ + t]);
      u = (u & 0x80000000u) ? ~u : (u | 0x80000000u);       // orderable uint
      key = ((unsigned long long)(~u) << 32) | (unsigned)t; // asc == depth desc
    }
    keys[t] = key;
    for (int i = t; i < NBOX; i += 256) {
      sw[i]    = ((const float4*)z_where)[b * NBOX + i];
      spres[i] = (unsigned char)(z_present[b * NBOX + i] != 0);
    }
    __syncthreads();
    for (int k = 2; k <= 256; k <<= 1) {
      for (int j = k >> 1; j > 0; j >>= 1) {
        int ixj = t ^ j;
        if (ixj > t) {
          unsigned long long a = keys[t], c = keys[ixj];
          bool asc = (t & k) == 0;
          if (asc ? (a > c) : (a < c)) { keys[t] = c; keys[ixj] = a; }
        }
        __syncthreads();
      }
    }

    const double step = 2.0 / 127.0;
    const double gx = (x == 127) ? 1.0 : ((double)x * step + (-1.0));
    const double gy = (y == 127) ? 1.0 : ((double)y * step + (-1.0));
    const int lane = t & 63;

    bool done = false;
    int  win  = -1;
    for (int e = 0; e < NBOX; e++) {
      if (__all((int)done)) break;
      const int o  = (int)(keys[e >> 2] & 0xFFFFFFFFull);
      const int bx = o * 4 + (e & 3);
      if (!spres[bx]) continue;                 // wave-uniform skip
      bool newly = false;
      if (!done) {
        float4 p = sw[bx];
        double w = fmax((double)p.z, 0.01);
        double h = fmax((double)p.w, 0.01);
        double tx = 2.0 * (double)p.x - 1.0;
        double ty = 2.0 * (double)p.y - 1.0;
        double u = (gx - tx) / w;
        double v = (gy - ty) / h;
        double px = (u + 1.0) * 0.5 * 63.0;
        double py = (v + 1.0) * 0.5 * 63.0;
        double fx = floor(px), fy = floor(py);
        double wx = px - fx, wy = py - fy;
        int x0 = (int)fx, y0 = (int)fy;
        int x1 = x0 + 1, y1 = y0 + 1;
        bool vx0 = (x0 >= 0) && (x0 < OBJS);
        bool vx1 = (x1 >= 0) && (x1 < OBJS);
        bool vy0 = (y0 >= 0) && (y0 < OBJS);
        bool vy1 = (y1 >= 0) && (y1 < OBJS);
        double w00 = (1.0 - wy) * (1.0 - wx);
        double w01 = (1.0 - wy) * wx;
        double w10 = wy * (1.0 - wx);
        double w11 = wy * wx;
        bool c00 = vy0 && vx0 && (w00 > 0.0);
        bool c01 = vy0 && vx1 && (w01 > 0.0);
        bool c10 = vy1 && vx0 && (w10 > 0.0);
        bool c11 = vy1 && vx1 && (w11 > 0.0);
        if (c00 | c01 | c10 | c11) { win = bx; done = true; newly = true; }
      }
      unsigned long long nm = __ballot((int)newly);
      if (nm != 0ull && lane == (int)__builtin_ctzll(nm)) {
        // all newly-covered lanes this iteration share the same object o
        int oi = b * NOBJ + o;
        if (atomicCAS(&used[oi], 0, 1) == 0) {
          int rr = atomicAdd(nrowsp, 1);
          rowobj[rr] = oi;
          remap[oi]  = rr;
        }
      }
    }
    pxwin[b * 16384 + y * 128 + x] = win;
  } else if (bid < ROLE_WIN + ROLE_G1) {
    // ---- role 1: H[r] = relu(Z[r] @ W1 + b1) -> bf16, original object order ----
    const int r = bid - ROLE_WIN;            // 0..539 = b*135 + obj
    if (t < ZW) zs[t] = Z[(size_t)r * ZW + t];
    __syncthreads();
    float a0 = b1[t], a1 = b1[t + 256];
#pragma unroll 8
    for (int k = 0; k < ZW; k++) {
      float z = zs[k];
      a0 += z * W1[(size_t)k * HIDN + t];
      a1 += z * W1[(size_t)k * HIDN + t + 256];
    }
    Hbf[(size_t)r * HIDN + t]       = f2bf(fmaxf(a0, 0.f));
    Hbf[(size_t)r * HIDN + t + 256] = f2bf(fmaxf(a1, 0.f));
  } else {
    // ---- role 2: W2 (512 x 12288 f32) -> W2T (12288 x 512 bf16) ----
    const int c  = bid - ROLE_WIN - ROLE_G1;
    const int n0 = (c % (NOUT / 64)) * 64;
    const int k0 = (c / (NOUT / 64)) * 64;
#pragma unroll
    for (int p = 0; p < 2; p++) {
      int kp = p * 16 + (t >> 4);        // k-pair 0..31
      int n4 = t & 15;
      int k  = k0 + kp * 2;
      float4 a = *(const float4*)&W2[(size_t)k * NOUT + n0 + n4 * 4];
      float4 b = *(const float4*)&W2[(size_t)(k + 1) * NOUT + n0 + n4 * 4];
      T[(n4*4 + 0) * 36 + kp] = (unsigned)f2bf(a.x) | ((unsigned)f2bf(b.x) << 16);
      T[(n4*4 + 1) * 36 + kp] = (unsigned)f2bf(a.y) | ((unsigned)f2bf(b.y) << 16);
      T[(n4*4 + 2) * 36 + kp] = (unsigned)f2bf(a.z) | ((unsigned)f2bf(b.z) << 16);
      T[(n4*4 + 3) * 36 + kp] = (unsigned)f2bf(a.w) | ((unsigned)f2bf(b.w) << 16);
    }
    __syncthreads();
#pragma unroll
    for (int p = 0; p < 2; p++) {
      int cc = p * 256 + t;
      int n = cc >> 3, ch = cc & 7;      // 8 chunks of 8 k (16B)
      uint4 v = *(const uint4*)&T[n * 36 + ch * 4];
      *(uint4*)&W2T[(size_t)(n0 + n) * HIDN + k0 + ch * 8] = v;
    }
  }
}

// ---------------------------------------------------------------------------
// K2: dec[row] = sigmoid(H[rowobj[row]] @ W2T^T + b2) for compact visible rows
// only.  bf16 MFMA 16x16x32, 128x128 tiles, 2-phase prefetch double-buffer.
// ---------------------------------------------------------------------------
__global__ __launch_bounds__(256) void k_gemm2_mfma(
    const unsigned short* __restrict__ Hbf,   // 540 x 512 bf16
    const unsigned short* __restrict__ W2T,   // 12288 x 512 bf16
    const float* __restrict__ b2,
    const int* __restrict__ nrowsp,
    const int* __restrict__ rowobj,
    float* __restrict__ dec)                  // 640 x 12288 f32 (compact rows)
{
  __shared__ unsigned short As[2][128 * 32];
  __shared__ unsigned short Bs[2][128 * 32];
  const int nr = *nrowsp;
  // XCD-aware bijective swizzle over the 480-block grid (480 = 8*60)
  int bid = (int)blockIdx.x;
  bid = (bid & 7) * 60 + (bid >> 3);
  const int m0 = (bid / 96) * 128;
  if (m0 >= nr) return;                       // prune dead m-tiles
  const int n0 = (bid % 96) * 128;

  const int t    = threadIdx.x;
  const int lane = t & 63, wv = t >> 6;
  const int wm = (wv & 1) * 64, wn = (wv >> 1) * 64;

  const int r0  = t >> 2;
  const int kc0 = (t & 3) ^ (r0 & 3);
  const int r1  = r0 + 64;
  const int kc1 = (t & 3) ^ (r1 & 3);

  const int ga0 = (m0 + r0 < nr) ? rowobj[m0 + r0] : 0;   // tail rows -> row 0 (unread)
  const int ga1 = (m0 + r1 < nr) ? rowobj[m0 + r1] : 0;
  const unsigned short* a0p = Hbf + (size_t)ga0 * HIDN + kc0 * 8;
  const unsigned short* a1p = Hbf + (size_t)ga1 * HIDN + kc1 * 8;
  const unsigned short* b0p = W2T + (size_t)(n0 + r0) * HIDN + kc0 * 8;
  const unsigned short* b1p = W2T + (size_t)(n0 + r1) * HIDN + kc1 * 8;

  const int fr = lane & 15;
  const int fj = lane >> 4;
  f32x4 acc[4][4] = {};

#define STAGE(buf, koff)                                                       \
  do {                                                                         \
    GLOAD_LDS16(a0p + (koff), &As[buf][t * 8]);                                \
    GLOAD_LDS16(a1p + (koff), &As[buf][(t + 256) * 8]);                        \
    GLOAD_LDS16(b0p + (koff), &Bs[buf][t * 8]);                                \
    GLOAD_LDS16(b1p + (koff), &Bs[buf][(t + 256) * 8]);                        \
  } while (0)

  STAGE(0, 0);
  __syncthreads();
  int cur = 0;
  for (int kt = 0; kt < HIDN / 32; ++kt) {
    if (kt < HIDN / 32 - 1) STAGE(cur ^ 1, (kt + 1) * 32);   // prefetch in flight
    bf16x8 av[4], bv[4];
#pragma unroll
    for (int mi = 0; mi < 4; mi++) {
      int row = wm + mi * 16 + fr;
      av[mi] = *(const bf16x8*)&As[cur][(row * 4 + (fj ^ (row & 3))) * 8];
    }
#pragma unroll
    for (int ni = 0; ni < 4; ni++) {
      int row = wn + ni * 16 + fr;
      bv[ni] = *(const bf16x8*)&Bs[cur][(row * 4 + (fj ^ (row & 3))) * 8];
    }
#pragma unroll
    for (int mi = 0; mi < 4; mi++)
#pragma unroll
      for (int ni = 0; ni < 4; ni++)
        acc[mi][ni] = __builtin_amdgcn_mfma_f32_16x16x32_bf16(av[mi], bv[ni], acc[mi][ni], 0, 0, 0);
    __syncthreads();   // drains prefetch (vmcnt) + guards LDS reuse
    cur ^= 1;
  }
#undef STAGE

#pragma unroll
  for (int ni = 0; ni < 4; ni++) {
    int col = n0 + wn + ni * 16 + fr;
    float bb = b2[col];
#pragma unroll
    for (int mi = 0; mi < 4; mi++) {
#pragma unroll
      for (int r = 0; r < 4; r++) {
        int row = m0 + wm + mi * 16 + fj * 4 + r;   // < 640, dec has 640 rows
        float v = acc[mi][ni][r] + bb;
        dec[(size_t)row * NOUT + col] = 1.0f / (1.0f + __expf(-v));
      }
    }
  }
}

// ---------------------------------------------------------------------------
// K3: light composite — winner is precomputed; recompute its fp64 taps
// (bit-identical math) and gather 12 floats from the compact dec row.
// ---------------------------------------------------------------------------
__global__ __launch_bounds__(256) void k_composite(
    const int* __restrict__ pxwin, const int* __restrict__ remap,
    const float* __restrict__ z_where, const float* __restrict__ dec,
    float* __restrict__ out)
{
#pragma clang fp contract(off)
  const int bid  = blockIdx.x;
  const int t    = threadIdx.x;
  const int b    = bid >> 6;
  const int tile = bid & 63;
  const int y = (tile >> 3) * 16 + (t >> 4);
  const int x = (tile & 7) * 16 + (t & 15);

  const int win = pxwin[b * 16384 + y * 128 + x];
  float o0 = 0.f, o1 = 0.f, o2 = 0.f;
  if (win >= 0) {
    const float4 p = ((const float4*)z_where)[b * NBOX + win];
    const double step = 2.0 / 127.0;
    const double gx = (x == 127) ? 1.0 : ((double)x * step + (-1.0));
    const double gy = (y == 127) ? 1.0 : ((double)y * step + (-1.0));
    double w = fmax((double)p.z, 0.01);
    double h = fmax((double)p.w, 0.01);
    double tx = 2.0 * (double)p.x - 1.0;
    double ty = 2.0 * (double)p.y - 1.0;
    double u = (gx - tx) / w;
    double v = (gy - ty) / h;
    double px = (u + 1.0) * 0.5 * 63.0;
    double py = (v + 1.0) * 0.5 * 63.0;
    double fx = floor(px), fy = floor(py);
    double wx = px - fx, wy = py - fy;
    int x0 = (int)fx, y0 = (int)fy;
    int x1 = x0 + 1, y1 = y0 + 1;
    bool vx0 = (x0 >= 0) && (x0 < OBJS);
    bool vx1 = (x1 >= 0) && (x1 < OBJS);
    bool vy0 = (y0 >= 0) && (y0 < OBJS);
    bool vy1 = (y1 >= 0) && (y1 < OBJS);
    double w00 = (1.0 - wy) * (1.0 - wx);
    double w01 = (1.0 - wy) * wx;
    double w10 = wy * (1.0 - wx);
    double w11 = wy * wx;
    bool c00 = vy0 && vx0 && (w00 > 0.0);
    bool c01 = vy0 && vx1 && (w01 > 0.0);
    bool c10 = vy1 && vx0 && (w10 > 0.0);
    bool c11 = vy1 && vx1 && (w11 > 0.0);
    const int row = remap[b * NOBJ + (win >> 2)];
    const float* g = dec + (size_t)row * NOUT;
    double s0 = 0.0, s1 = 0.0, s2 = 0.0;
    if (c00) { int o = y0*64 + x0; s0 += g[o]*w00; s1 += g[4096+o]*w00; s2 += g[8192+o]*w00; }
    if (c01) { int o = y0*64 + x1; s0 += g[o]*w01; s1 += g[4096+o]*w01; s2 += g[8192+o]*w01; }
    if (c10) { int o = y1*64 + x0; s0 += g[o]*w10; s1 += g[4096+o]*w10; s2 += g[8192+o]*w10; }
    if (c11) { int o = y1*64 + x1; s0 += g[o]*w11; s1 += g[4096+o]*w11; s2 += g[8192+o]*w11; }
    o0 = (float)s0; o1 = (float)s1; o2 = (float)s2;
  }
  const int ob = b * 3 * 16384 + y * 128 + x;    // (B,3,128,128)
  out[ob]         = o0;
  out[ob + 16384] = o1;
  out[ob + 32768] = o2;
}

// ---------------------------------------------------------------------------
extern "C" void kernel_launch(void* const* d_in, const int* in_sizes, int n_in,
                              void* d_out, int out_size, void* d_ws, size_t ws_size,
                              hipStream_t stream) {
  (void)in_sizes; (void)n_in; (void)out_size; (void)ws_size;
  const float* z_what    = (const float*)d_in[0];
  const float* z_where   = (const float*)d_in[1];
  const float* z_depth   = (const float*)d_in[2];
  const float* W1        = (const float*)d_in[3];
  const float* b1        = (const float*)d_in[4];
  const float* W2        = (const float*)d_in[5];
  const float* b2        = (const float*)d_in[6];
  const int*   z_present = (const int*)d_in[7];
  float* out = (float*)d_out;
  char* ws = (char*)d_ws;

  int*            nrowsp = (int*)(ws + OFF_NROWS);
  int*            used   = (int*)(ws + OFF_USED);
  int*            remap  = (int*)(ws + OFF_REMAP);
  int*            rowobj = (int*)(ws + OFF_ROWOBJ);
  int*            pxwin  = (int*)(ws + OFF_PXWIN);
  unsigned short* Hbf    = (unsigned short*)(ws + OFF_HBF);
  unsigned short* W2T    = (unsigned short*)(ws + OFF_W2T);
  float*          dec    = (float*)(ws + OFF_DEC);

  // zero nrows + used[] (workspace is poisoned between iterations)
  hipMemsetAsync(ws + OFF_NROWS, 0, 2560, stream);

  k_pre<<<dim3(PRE_BLOCKS), dim3(256), 0, stream>>>(
      z_depth, z_where, z_present, z_what, W1, b1, W2,
      nrowsp, used, remap, rowobj, pxwin, Hbf, W2T);
  k_gemm2_mfma<<<dim3((NOUT / 128) * 5), dim3(256), 0, stream>>>(
      Hbf, W2T, b2, nrowsp, rowobj, dec);
  k_composite<<<dim3(256), dim3(256), 0, stream>>>(pxwin, remap, z_where, dec, out);
}

// Round 2
// 124.745 us; speedup vs baseline: 1.2121x; 1.2121x over previous
//
#include <hip/hip_runtime.h>
#include <hip/hip_bf16.h>
#include <math.h>

#define NBOX  540      // total boxes per batch
#define NOBJ  135      // unique objects per batch
#define ZW    64
#define HIDN  512
#define NOUT  12288    // 3*64*64
#define OBJS  64
#define BATCH 4

// fused K1 block roles: [winner 256 | gemm1 540 | W2 cvt 1536]
#define ROLE_WIN   256
#define ROLE_G1    540
#define ROLE_CVT   ((NOUT / 64) * (HIDN / 64))   // 1536
#define PRE_BLOCKS (ROLE_WIN + ROLE_G1 + ROLE_CVT)

// workspace layout (bytes), 256-aligned
#define OFF_NROWS  0u          // int
#define OFF_USED   256u        // int[540]   -> 2416
#define OFF_REMAP  2560u       // int[540]   -> 4720
#define OFF_ROWOBJ 4864u       // int[640]   -> 7424
#define OFF_PXWIN  7680u       // int[65536] -> 269824
#define OFF_HBF    269824u     // ushort 640*512 = 655360 -> 925184
#define OFF_W2T    925184u     // ushort 12288*512 = 12582912 -> 13508096
#define OFF_DEC    13508096u   // float 640*12288 = 31457280 -> ~45 MB

typedef short  bf16x8 __attribute__((ext_vector_type(8)));
typedef float  f32x4  __attribute__((ext_vector_type(4)));

struct F4 { float x, y, z, w; };   // POD float4 (union-safe)

#define GLOAD_LDS16(gp, lp)                                                    \
  __builtin_amdgcn_global_load_lds(                                            \
      (const __attribute__((address_space(1))) void*)(gp),                     \
      (__attribute__((address_space(3))) void*)(lp), 16, 0, 0)

__device__ __forceinline__ unsigned short f2bf(float x) {
  __hip_bfloat16 h = __float2bfloat16(x);
  return *(unsigned short*)&h;
}

// ---------------------------------------------------------------------------
// K1: fused {painter visibility search | gemm1 | W2 cvt+T}
// Winner role: per 16x16 px tile: bitonic-sort the batch's 135 depths, compact
// present boxes in depth order into LDS with conservative integer pixel
// bboxes, then walk candidates front-to-back.  Per-candidate skip is a
// wave-uniform bbox test; the coverage decision itself is the exact fp64
// sequence (px,py in (-1,64) is bit-identical to the 4-tap c00|c01|c10|c11).
// ---------------------------------------------------------------------------
__global__ __launch_bounds__(256) void k_pre(
    const float* __restrict__ z_depth,   // B*135
    const float* __restrict__ z_where,   // B*540*4
    const int*   __restrict__ z_present, // B*540
    const float* __restrict__ Z,         // B*135*64 z_what
    const float* __restrict__ W1,        // 64*512
    const float* __restrict__ b1,        // 512
    const float* __restrict__ W2,        // 512*12288
    int* __restrict__ nrowsp,            // compact visible-row count (pre-zeroed)
    int* __restrict__ used,              // int[540] (pre-zeroed)
    int* __restrict__ remap,             // (b*135+obj) -> compact row
    int* __restrict__ rowobj,            // compact row -> (b*135+obj)
    int* __restrict__ pxwin,             // per-pixel winning box (orig id) or -1
    unsigned short* __restrict__ Hbf,    // 540*512 bf16
    unsigned short* __restrict__ W2T)    // 12288*512 bf16
{
  __shared__ union ShMem {
    struct {
      unsigned long long keys[256];   // 2048
      F4       cw[NBOX];              // 8640  compacted sorted present boxes
      unsigned cbb[NBOX];             // 2160  packed bbox xlo|xhi|ylo|yhi
      int      cbx[NBOX];             // 2160  original box index
    } win;                            // 15008
    unsigned T[64 * 36];              // 9216  (cvt role)
    float    zs[ZW];                  // 256   (gemm1 role)
  } u;
  __shared__ int wsums[4], woff[4], nPs;

  const int bid = blockIdx.x;
  const int t   = threadIdx.x;

  if (bid < ROLE_WIN) {
    // ---- role 0: visibility search ----
#pragma clang fp contract(off)
    const int b    = bid >> 6;
    const int tile = bid & 63;
    const int lane = t & 63, wv = t >> 6;
    const int y = (tile >> 3) * 16 + (t >> 4);
    const int x = (tile & 7) * 16 + (t & 15);

    unsigned long long key = ~0ull;
    if (t < NOBJ) {
      unsigned uu = __float_as_uint(z_depth[b * NOBJ + t]);
      uu = (uu & 0x80000000u) ? ~uu : (uu | 0x80000000u);     // orderable uint
      key = ((unsigned long long)(~uu) << 32) | (unsigned)t;  // asc == depth desc
    }
    u.win.keys[t] = key;
    __syncthreads();
    for (int k = 2; k <= 256; k <<= 1) {
      for (int j = k >> 1; j > 0; j >>= 1) {
        int ixj = t ^ j;
        if (ixj > t) {
          unsigned long long a = u.win.keys[t], c = u.win.keys[ixj];
          bool asc = (t & k) == 0;
          if (asc ? (a > c) : (a < c)) { u.win.keys[t] = c; u.win.keys[ixj] = a; }
        }
        __syncthreads();
      }
    }

    // compact present boxes (sorted order) + conservative pixel bboxes
    int boxq[3], presq[3], cnt = 0;
#pragma unroll
    for (int q = 0; q < 3; q++) {
      int e = 3 * t + q;
      presq[q] = 0; boxq[q] = 0;
      if (e < NBOX) {
        int o  = (int)(u.win.keys[e >> 2] & 0xFFFFFFFFull);
        int bx = o * 4 + (e & 3);
        boxq[q]  = bx;
        presq[q] = (z_present[b * NBOX + bx] != 0) ? 1 : 0;
        cnt += presq[q];
      }
    }
    int incl = cnt;
#pragma unroll
    for (int o = 1; o < 64; o <<= 1) {
      int vprev = __shfl_up(incl, o, 64);
      if (lane >= o) incl += vprev;
    }
    if (lane == 63) wsums[wv] = incl;
    __syncthreads();
    if (t == 0) {
      int a = 0;
#pragma unroll
      for (int i = 0; i < 4; i++) { woff[i] = a; a += wsums[i]; }
      nPs = a;
    }
    __syncthreads();
    int slot = woff[wv] + incl - cnt;
#pragma unroll
    for (int q = 0; q < 3; q++) {
      if (presq[q]) {
        int bx = boxq[q];
        F4 p = *(const F4*)&z_where[((size_t)b * NBOX + bx) * 4];
        double w  = fmax((double)p.z, 0.01);
        double h  = fmax((double)p.w, 0.01);
        double tx = 2.0 * (double)p.x - 1.0;
        double ty = 2.0 * (double)p.y - 1.0;
        const double S = 65.0 / 63.0;       // coverage iff |u| < 65/63 (real)
        int xlo = (int)floor((tx - w * S + 1.0) * 63.5) - 1;   // 63.5 = 1/step
        int xhi = (int)floor((tx + w * S + 1.0) * 63.5) + 2;
        int ylo = (int)floor((ty - h * S + 1.0) * 63.5) - 1;
        int yhi = (int)floor((ty + h * S + 1.0) * 63.5) + 2;
        xlo = max(xlo, 0); ylo = max(ylo, 0);
        xhi = min(xhi, 127); yhi = min(yhi, 127);
        unsigned bb = (xhi < xlo || yhi < ylo) ? 0xFFu   // sentinel: always skip
                    : ((unsigned)xlo | ((unsigned)xhi << 8) |
                       ((unsigned)ylo << 16) | ((unsigned)yhi << 24));
        u.win.cw[slot]  = p;
        u.win.cbb[slot] = bb;
        u.win.cbx[slot] = bx;
        slot++;
      }
    }
    __syncthreads();

    const int nP = nPs;
    const double step = 2.0 / 127.0;
    const double gx = (x == 127) ? 1.0 : ((double)x * step + (-1.0));
    const double gy = (y == 127) ? 1.0 : ((double)y * step + (-1.0));
    const int tx0 = (tile & 7) * 16, tx1 = tx0 + 15;
    const int wy0 = (tile >> 3) * 16 + wv * 4, wy1 = wy0 + 3;  // wave's 16x4 strip

    bool done = false;
    int  win  = -1;
    for (int j = 0; j < nP; j++) {
      if (__all((int)done)) break;
      unsigned bb = u.win.cbb[j];
      int bxlo = (int)(bb & 255u),         bxhi = (int)((bb >> 8) & 255u);
      int bylo = (int)((bb >> 16) & 255u), byhi = (int)(bb >> 24);
      if (bxhi < tx0 || bxlo > tx1 || byhi < wy0 || bylo > wy1) continue;
      bool newly = false;
      if (!done) {
        F4 p = u.win.cw[j];
        double w  = fmax((double)p.z, 0.01);
        double h  = fmax((double)p.w, 0.01);
        double tx = 2.0 * (double)p.x - 1.0;
        double ty = 2.0 * (double)p.y - 1.0;
        double uu = (gx - tx) / w;
        double vv = (gy - ty) / h;
        double px = (uu + 1.0) * 0.5 * 63.0;
        double py = (vv + 1.0) * 0.5 * 63.0;
        // bit-identical to c00|c01|c10|c11 of the 4-tap predicate
        if (px > -1.0 && px < 64.0 && py > -1.0 && py < 64.0) {
          win = u.win.cbx[j]; done = true; newly = true;
        }
      }
      unsigned long long nm = __ballot((int)newly);
      if (nm != 0ull && lane == (int)__builtin_ctzll(nm)) {
        int oi = b * NOBJ + (win >> 2);     // this lane is newly => win = cbx[j]
        if (atomicCAS(&used[oi], 0, 1) == 0) {
          int rr = atomicAdd(nrowsp, 1);
          rowobj[rr] = oi;
          remap[oi]  = rr;
        }
      }
    }
    pxwin[b * 16384 + y * 128 + x] = win;
  } else if (bid < ROLE_WIN + ROLE_G1) {
    // ---- role 1: H[r] = relu(Z[r] @ W1 + b1) -> bf16, original object order ----
    const int r = bid - ROLE_WIN;            // 0..539 = b*135 + obj
    if (t < ZW) u.zs[t] = Z[(size_t)r * ZW + t];
    __syncthreads();
    float a0 = b1[t], a1 = b1[t + 256];
#pragma unroll 8
    for (int k = 0; k < ZW; k++) {
      float z = u.zs[k];
      a0 += z * W1[(size_t)k * HIDN + t];
      a1 += z * W1[(size_t)k * HIDN + t + 256];
    }
    Hbf[(size_t)r * HIDN + t]       = f2bf(fmaxf(a0, 0.f));
    Hbf[(size_t)r * HIDN + t + 256] = f2bf(fmaxf(a1, 0.f));
  } else {
    // ---- role 2: W2 (512 x 12288 f32) -> W2T (12288 x 512 bf16) ----
    const int c  = bid - ROLE_WIN - ROLE_G1;
    const int n0 = (c % (NOUT / 64)) * 64;
    const int k0 = (c / (NOUT / 64)) * 64;
#pragma unroll
    for (int p = 0; p < 2; p++) {
      int kp = p * 16 + (t >> 4);        // k-pair 0..31
      int n4 = t & 15;
      int k  = k0 + kp * 2;
      float4 a = *(const float4*)&W2[(size_t)k * NOUT + n0 + n4 * 4];
      float4 b = *(const float4*)&W2[(size_t)(k + 1) * NOUT + n0 + n4 * 4];
      u.T[(n4*4 + 0) * 36 + kp] = (unsigned)f2bf(a.x) | ((unsigned)f2bf(b.x) << 16);
      u.T[(n4*4 + 1) * 36 + kp] = (unsigned)f2bf(a.y) | ((unsigned)f2bf(b.y) << 16);
      u.T[(n4*4 + 2) * 36 + kp] = (unsigned)f2bf(a.z) | ((unsigned)f2bf(b.z) << 16);
      u.T[(n4*4 + 3) * 36 + kp] = (unsigned)f2bf(a.w) | ((unsigned)f2bf(b.w) << 16);
    }
    __syncthreads();
#pragma unroll
    for (int p = 0; p < 2; p++) {
      int cc = p * 256 + t;
      int n = cc >> 3, ch = cc & 7;      // 8 chunks of 8 k (16B)
      uint4 v = *(const uint4*)&u.T[n * 36 + ch * 4];
      *(uint4*)&W2T[(size_t)(n0 + n) * HIDN + k0 + ch * 8] = v;
    }
  }
}

// ---------------------------------------------------------------------------
// K2: dec[row] = sigmoid(H[rowobj[row]] @ W2T^T + b2) for compact visible rows
// only.  bf16 MFMA 16x16x32, 128x128 tiles, 2-phase prefetch double-buffer.
// ---------------------------------------------------------------------------
__global__ __launch_bounds__(256) void k_gemm2_mfma(
    const unsigned short* __restrict__ Hbf,   // 540 x 512 bf16
    const unsigned short* __restrict__ W2T,   // 12288 x 512 bf16
    const float* __restrict__ b2,
    const int* __restrict__ nrowsp,
    const int* __restrict__ rowobj,
    float* __restrict__ dec)                  // 640 x 12288 f32 (compact rows)
{
  __shared__ unsigned short As[2][128 * 32];
  __shared__ unsigned short Bs[2][128 * 32];
  const int nr = *nrowsp;
  // XCD-aware bijective swizzle over the 480-block grid (480 = 8*60)
  int bid = (int)blockIdx.x;
  bid = (bid & 7) * 60 + (bid >> 3);
  const int m0 = (bid / 96) * 128;
  if (m0 >= nr) return;                       // prune dead m-tiles
  const int n0 = (bid % 96) * 128;

  const int t    = threadIdx.x;
  const int lane = t & 63, wv = t >> 6;
  const int wm = (wv & 1) * 64, wn = (wv >> 1) * 64;

  const int r0  = t >> 2;
  const int kc0 = (t & 3) ^ (r0 & 3);
  const int r1  = r0 + 64;
  const int kc1 = (t & 3) ^ (r1 & 3);

  const int ga0 = (m0 + r0 < nr) ? rowobj[m0 + r0] : 0;   // tail rows -> row 0 (unread)
  const int ga1 = (m0 + r1 < nr) ? rowobj[m0 + r1] : 0;
  const unsigned short* a0p = Hbf + (size_t)ga0 * HIDN + kc0 * 8;
  const unsigned short* a1p = Hbf + (size_t)ga1 * HIDN + kc1 * 8;
  const unsigned short* b0p = W2T + (size_t)(n0 + r0) * HIDN + kc0 * 8;
  const unsigned short* b1p = W2T + (size_t)(n0 + r1) * HIDN + kc1 * 8;

  const int fr = lane & 15;
  const int fj = lane >> 4;
  f32x4 acc[4][4] = {};

#define STAGE(buf, koff)                                                       \
  do {                                                                         \
    GLOAD_LDS16(a0p + (koff), &As[buf][t * 8]);                                \
    GLOAD_LDS16(a1p + (koff), &As[buf][(t + 256) * 8]);                        \
    GLOAD_LDS16(b0p + (koff), &Bs[buf][t * 8]);                                \
    GLOAD_LDS16(b1p + (koff), &Bs[buf][(t + 256) * 8]);                        \
  } while (0)

  STAGE(0, 0);
  __syncthreads();
  int cur = 0;
  for (int kt = 0; kt < HIDN / 32; ++kt) {
    if (kt < HIDN / 32 - 1) STAGE(cur ^ 1, (kt + 1) * 32);   // prefetch in flight
    bf16x8 av[4], bv[4];
#pragma unroll
    for (int mi = 0; mi < 4; mi++) {
      int row = wm + mi * 16 + fr;
      av[mi] = *(const bf16x8*)&As[cur][(row * 4 + (fj ^ (row & 3))) * 8];
    }
#pragma unroll
    for (int ni = 0; ni < 4; ni++) {
      int row = wn + ni * 16 + fr;
      bv[ni] = *(const bf16x8*)&Bs[cur][(row * 4 + (fj ^ (row & 3))) * 8];
    }
#pragma unroll
    for (int mi = 0; mi < 4; mi++)
#pragma unroll
      for (int ni = 0; ni < 4; ni++)
        acc[mi][ni] = __builtin_amdgcn_mfma_f32_16x16x32_bf16(av[mi], bv[ni], acc[mi][ni], 0, 0, 0);
    __syncthreads();   // drains prefetch (vmcnt) + guards LDS reuse
    cur ^= 1;
  }
#undef STAGE

#pragma unroll
  for (int ni = 0; ni < 4; ni++) {
    int col = n0 + wn + ni * 16 + fr;
    float bb = b2[col];
#pragma unroll
    for (int mi = 0; mi < 4; mi++) {
#pragma unroll
      for (int r = 0; r < 4; r++) {
        int row = m0 + wm + mi * 16 + fj * 4 + r;   // < 640, dec has 640 rows
        float v = acc[mi][ni][r] + bb;
        dec[(size_t)row * NOUT + col] = 1.0f / (1.0f + __expf(-v));
      }
    }
  }
}

// ---------------------------------------------------------------------------
// K3: light composite — winner is precomputed; recompute its fp64 taps
// (bit-identical math) and gather 12 floats from the compact dec row.
// ---------------------------------------------------------------------------
__global__ __launch_bounds__(256) void k_composite(
    const int* __restrict__ pxwin, const int* __restrict__ remap,
    const float* __restrict__ z_where, const float* __restrict__ dec,
    float* __restrict__ out)
{
#pragma clang fp contract(off)
  const int bid  = blockIdx.x;
  const int t    = threadIdx.x;
  const int b    = bid >> 6;
  const int tile = bid & 63;
  const int y = (tile >> 3) * 16 + (t >> 4);
  const int x = (tile & 7) * 16 + (t & 15);

  const int win = pxwin[b * 16384 + y * 128 + x];
  float o0 = 0.f, o1 = 0.f, o2 = 0.f;
  if (win >= 0) {
    const F4 p = *(const F4*)&z_where[((size_t)b * NBOX + win) * 4];
    const double step = 2.0 / 127.0;
    const double gx = (x == 127) ? 1.0 : ((double)x * step + (-1.0));
    const double gy = (y == 127) ? 1.0 : ((double)y * step + (-1.0));
    double w = fmax((double)p.z, 0.01);
    double h = fmax((double)p.w, 0.01);
    double tx = 2.0 * (double)p.x - 1.0;
    double ty = 2.0 * (double)p.y - 1.0;
    double u = (gx - tx) / w;
    double v = (gy - ty) / h;
    double px = (u + 1.0) * 0.5 * 63.0;
    double py = (v + 1.0) * 0.5 * 63.0;
    double fx = floor(px), fy = floor(py);
    double wx = px - fx, wy = py - fy;
    int x0 = (int)fx, y0 = (int)fy;
    int x1 = x0 + 1, y1 = y0 + 1;
    bool vx0 = (x0 >= 0) && (x0 < OBJS);
    bool vx1 = (x1 >= 0) && (x1 < OBJS);
    bool vy0 = (y0 >= 0) && (y0 < OBJS);
    bool vy1 = (y1 >= 0) && (y1 < OBJS);
    double w00 = (1.0 - wy) * (1.0 - wx);
    double w01 = (1.0 - wy) * wx;
    double w10 = wy * (1.0 - wx);
    double w11 = wy * wx;
    bool c00 = vy0 && vx0 && (w00 > 0.0);
    bool c01 = vy0 && vx1 && (w01 > 0.0);
    bool c10 = vy1 && vx0 && (w10 > 0.0);
    bool c11 = vy1 && vx1 && (w11 > 0.0);
    const int row = remap[b * NOBJ + (win >> 2)];
    const float* g = dec + (size_t)row * NOUT;
    double s0 = 0.0, s1 = 0.0, s2 = 0.0;
    if (c00) { int o = y0*64 + x0; s0 += g[o]*w00; s1 += g[4096+o]*w00; s2 += g[8192+o]*w00; }
    if (c01) { int o = y0*64 + x1; s0 += g[o]*w01; s1 += g[4096+o]*w01; s2 += g[8192+o]*w01; }
    if (c10) { int o = y1*64 + x0; s0 += g[o]*w10; s1 += g[4096+o]*w10; s2 += g[8192+o]*w10; }
    if (c11) { int o = y1*64 + x1; s0 += g[o]*w11; s1 += g[4096+o]*w11; s2 += g[8192+o]*w11; }
    o0 = (float)s0; o1 = (float)s1; o2 = (float)s2;
  }
  const int ob = b * 3 * 16384 + y * 128 + x;    // (B,3,128,128)
  out[ob]         = o0;
  out[ob + 16384] = o1;
  out[ob + 32768] = o2;
}

// ---------------------------------------------------------------------------
extern "C" void kernel_launch(void* const* d_in, const int* in_sizes, int n_in,
                              void* d_out, int out_size, void* d_ws, size_t ws_size,
                              hipStream_t stream) {
  (void)in_sizes; (void)n_in; (void)out_size; (void)ws_size;
  const float* z_what    = (const float*)d_in[0];
  const float* z_where   = (const float*)d_in[1];
  const float* z_depth   = (const float*)d_in[2];
  const float* W1        = (const float*)d_in[3];
  const float* b1        = (const float*)d_in[4];
  const float* W2        = (const float*)d_in[5];
  const float* b2        = (const float*)d_in[6];
  const int*   z_present = (const int*)d_in[7];
  float* out = (float*)d_out;
  char* ws = (char*)d_ws;

  int*            nrowsp = (int*)(ws + OFF_NROWS);
  int*            used   = (int*)(ws + OFF_USED);
  int*            remap  = (int*)(ws + OFF_REMAP);
  int*            rowobj = (int*)(ws + OFF_ROWOBJ);
  int*            pxwin  = (int*)(ws + OFF_PXWIN);
  unsigned short* Hbf    = (unsigned short*)(ws + OFF_HBF);
  unsigned short* W2T    = (unsigned short*)(ws + OFF_W2T);
  float*          dec    = (float*)(ws + OFF_DEC);

  // zero nrows + used[] (workspace is poisoned between iterations)
  hipMemsetAsync(ws + OFF_NROWS, 0, 2560, stream);

  k_pre<<<dim3(PRE_BLOCKS), dim3(256), 0, stream>>>(
      z_depth, z_where, z_present, z_what, W1, b1, W2,
      nrowsp, used, remap, rowobj, pxwin, Hbf, W2T);
  k_gemm2_mfma<<<dim3((NOUT / 128) * 5), dim3(256), 0, stream>>>(
      Hbf, W2T, b2, nrowsp, rowobj, dec);
  k_composite<<<dim3(256), dim3(256), 0, stream>>>(pxwin, remap, z_where, dec, out);
}

// Round 3
// 123.383 us; speedup vs baseline: 1.2254x; 1.0110x over previous
//
#include <hip/hip_runtime.h>
#include <hip/hip_bf16.h>
#include <math.h>

#define NBOX  540      // total boxes per batch
#define NOBJ  135      // unique objects per batch
#define ZW    64
#define HIDN  512
#define NOUT  12288    // 3*64*64
#define OBJS  64
#define BATCH 4

// fused K1 block roles: [winner 256 | gemm1 540 | W2 cvt 1536]
#define ROLE_WIN   256
#define ROLE_G1    540
#define ROLE_CVT   ((NOUT / 64) * (HIDN / 64))   // 1536
#define PRE_BLOCKS (ROLE_WIN + ROLE_G1 + ROLE_CVT)

// workspace layout (bytes), 256-aligned
#define OFF_NROWS  0u          // int
#define OFF_USED   256u        // int[540]   -> 2416
#define OFF_REMAP  2560u       // int[540]   -> 4720
#define OFF_ROWOBJ 4864u       // int[640]   -> 7424
#define OFF_PXWIN  7680u       // int[65536] -> 269824
#define OFF_HBF    269824u     // ushort 640*512 = 655360 -> 925184
#define OFF_W2T    925184u     // ushort 12288*512 = 12582912 -> 13508096
#define OFF_DEC    13508096u   // float 640*12288 = 31457280 -> ~45 MB

typedef short  bf16x8 __attribute__((ext_vector_type(8)));
typedef float  f32x4  __attribute__((ext_vector_type(4)));

struct F4 { float x, y, z, w; };   // POD float4 (union-safe)

#define GLOAD_LDS16(gp, lp)                                                    \
  __builtin_amdgcn_global_load_lds(                                            \
      (const __attribute__((address_space(1))) void*)(gp),                     \
      (__attribute__((address_space(3))) void*)(lp), 16, 0, 0)

__device__ __forceinline__ unsigned short f2bf(float x) {
  __hip_bfloat16 h = __float2bfloat16(x);
  return *(unsigned short*)&h;
}

// ---------------------------------------------------------------------------
// K1: fused {painter visibility search | gemm1 | W2 cvt+T}
// Winner role: per 16x16 px tile: bitonic-sort the batch's 135 depths, compact
// present boxes in depth order into LDS with (a) conservative integer pixel
// bboxes (wave-uniform skip) and (b) f32 center/half-width for a margin-based
// prefilter.  Coverage in real arithmetic is |gx-tx| < w*65/63 (same for y);
// the f32 test with +-1e-4 rel / 2e-6 abs margins decides all but ~1e-4 of
// candidates; borderline ones run the original exact fp64 divide sequence, so
// every decision is bit-identical to the reference predicate.
// ---------------------------------------------------------------------------
__global__ __launch_bounds__(256) void k_pre(
    const float* __restrict__ z_depth,   // B*135
    const float* __restrict__ z_where,   // B*540*4
    const int*   __restrict__ z_present, // B*540
    const float* __restrict__ Z,         // B*135*64 z_what
    const float* __restrict__ W1,        // 64*512
    const float* __restrict__ b1,        // 512
    const float* __restrict__ W2,        // 512*12288
    int* __restrict__ nrowsp,            // compact visible-row count (pre-zeroed)
    int* __restrict__ used,              // int[540] (pre-zeroed)
    int* __restrict__ remap,             // (b*135+obj) -> compact row
    int* __restrict__ rowobj,            // compact row -> (b*135+obj)
    int* __restrict__ pxwin,             // per-pixel winning box (orig id) or -1
    unsigned short* __restrict__ Hbf,    // 540*512 bf16
    unsigned short* __restrict__ W2T)    // 12288*512 bf16
{
  __shared__ union ShMem {
    struct {
      unsigned long long keys[256];   // 2048
      F4       cf[NBOX];              // 8640  f32 {tx, ty, rx, ry} per candidate
      unsigned cbb[NBOX];             // 2160  packed bbox xlo|xhi|ylo|yhi
      int      cbx[NBOX];             // 2160  original box index
    } win;                            // 15008
    unsigned T[64 * 36];              // 9216  (cvt role)
    float    zs[ZW];                  // 256   (gemm1 role)
  } u;
  __shared__ int wsums[4], woff[4], nPs;

  const int bid = blockIdx.x;
  const int t   = threadIdx.x;

  if (bid < ROLE_WIN) {
    // ---- role 0: visibility search ----
#pragma clang fp contract(off)
    const int b    = bid >> 6;
    const int tile = bid & 63;
    const int lane = t & 63, wv = t >> 6;
    const int y = (tile >> 3) * 16 + (t >> 4);
    const int x = (tile & 7) * 16 + (t & 15);

    unsigned long long key = ~0ull;
    if (t < NOBJ) {
      unsigned uu = __float_as_uint(z_depth[b * NOBJ + t]);
      uu = (uu & 0x80000000u) ? ~uu : (uu | 0x80000000u);     // orderable uint
      key = ((unsigned long long)(~uu) << 32) | (unsigned)t;  // asc == depth desc
    }
    u.win.keys[t] = key;
    __syncthreads();
    for (int k = 2; k <= 256; k <<= 1) {
      for (int j = k >> 1; j > 0; j >>= 1) {
        int ixj = t ^ j;
        if (ixj > t) {
          unsigned long long a = u.win.keys[t], c = u.win.keys[ixj];
          bool asc = (t & k) == 0;
          if (asc ? (a > c) : (a < c)) { u.win.keys[t] = c; u.win.keys[ixj] = a; }
        }
        __syncthreads();
      }
    }

    // compact present boxes (sorted order) + bboxes + f32 prefilter params
    int boxq[3], presq[3], cnt = 0;
#pragma unroll
    for (int q = 0; q < 3; q++) {
      int e = 3 * t + q;
      presq[q] = 0; boxq[q] = 0;
      if (e < NBOX) {
        int o  = (int)(u.win.keys[e >> 2] & 0xFFFFFFFFull);
        int bx = o * 4 + (e & 3);
        boxq[q]  = bx;
        presq[q] = (z_present[b * NBOX + bx] != 0) ? 1 : 0;
        cnt += presq[q];
      }
    }
    int incl = cnt;
#pragma unroll
    for (int o = 1; o < 64; o <<= 1) {
      int vprev = __shfl_up(incl, o, 64);
      if (lane >= o) incl += vprev;
    }
    if (lane == 63) wsums[wv] = incl;
    __syncthreads();
    if (t == 0) {
      int a = 0;
#pragma unroll
      for (int i = 0; i < 4; i++) { woff[i] = a; a += wsums[i]; }
      nPs = a;
    }
    __syncthreads();
    int slot = woff[wv] + incl - cnt;
#pragma unroll
    for (int q = 0; q < 3; q++) {
      if (presq[q]) {
        int bx = boxq[q];
        F4 p = *(const F4*)&z_where[((size_t)b * NBOX + bx) * 4];
        double w  = fmax((double)p.z, 0.01);
        double h  = fmax((double)p.w, 0.01);
        double tx = 2.0 * (double)p.x - 1.0;
        double ty = 2.0 * (double)p.y - 1.0;
        const double S = 65.0 / 63.0;       // coverage iff |gx-tx| < w*S (real)
        int xlo = (int)floor((tx - w * S + 1.0) * 63.5) - 1;   // 63.5 = 1/step
        int xhi = (int)floor((tx + w * S + 1.0) * 63.5) + 2;
        int ylo = (int)floor((ty - h * S + 1.0) * 63.5) - 1;
        int yhi = (int)floor((ty + h * S + 1.0) * 63.5) + 2;
        xlo = max(xlo, 0); ylo = max(ylo, 0);
        xhi = min(xhi, 127); yhi = min(yhi, 127);
        unsigned bb = (xhi < xlo || yhi < ylo) ? 0xFFu   // sentinel: always skip
                    : ((unsigned)xlo | ((unsigned)xhi << 8) |
                       ((unsigned)ylo << 16) | ((unsigned)yhi << 24));
        F4 f;
        f.x = (float)tx; f.y = (float)ty;
        f.z = (float)(w * S); f.w = (float)(h * S);
        u.win.cf[slot]  = f;
        u.win.cbb[slot] = bb;
        u.win.cbx[slot] = bx;
        slot++;
      }
    }
    __syncthreads();

    const int nP = nPs;
    const double step = 2.0 / 127.0;
    const double gx = (x == 127) ? 1.0 : ((double)x * step + (-1.0));
    const double gy = (y == 127) ? 1.0 : ((double)y * step + (-1.0));
    const float gxf = (float)gx, gyf = (float)gy;
    const int tx0 = (tile & 7) * 16, tx1 = tx0 + 15;
    const int wy0 = (tile >> 3) * 16 + wv * 4, wy1 = wy0 + 3;  // wave's 16x4 strip

    bool done = false;
    int  win  = -1;
    for (int j = 0; j < nP; j++) {
      if (__all((int)done)) break;
      unsigned bb = u.win.cbb[j];
      int bxlo = (int)(bb & 255u),         bxhi = (int)((bb >> 8) & 255u);
      int bylo = (int)((bb >> 16) & 255u), byhi = (int)(bb >> 24);
      if (bxhi < tx0 || bxlo > tx1 || byhi < wy0 || bylo > wy1) continue;
      bool newly = false;
      if (!done) {
        F4 f = u.win.cf[j];
        float dx = fabsf(gxf - f.x), dy = fabsf(gyf - f.y);
        // conservative margins: f32 pipeline error <= ~5e-7, band = 1e-4 rel + 2e-6 abs
        bool in_lo = (dx < f.z * 0.9999f - 2e-6f) & (dy < f.w * 0.9999f - 2e-6f);
        bool in_hi = (dx < f.z * 1.0001f + 2e-6f) & (dy < f.w * 1.0001f + 2e-6f);
        bool cov;
        if (in_lo) {
          cov = true;                       // definitely covered
        } else if (!in_hi) {
          cov = false;                      // definitely not covered
        } else {
          // borderline (~1e-4 prob): exact fp64 sequence, bit-identical to ref
          F4 p = *(const F4*)&z_where[((size_t)b * NBOX + u.win.cbx[j]) * 4];
          double w  = fmax((double)p.z, 0.01);
          double h  = fmax((double)p.w, 0.01);
          double tx = 2.0 * (double)p.x - 1.0;
          double ty = 2.0 * (double)p.y - 1.0;
          double uu = (gx - tx) / w;
          double vv = (gy - ty) / h;
          double px = (uu + 1.0) * 0.5 * 63.0;
          double py = (vv + 1.0) * 0.5 * 63.0;
          cov = (px > -1.0) && (px < 64.0) && (py > -1.0) && (py < 64.0);
        }
        if (cov) { win = u.win.cbx[j]; done = true; newly = true; }
      }
      unsigned long long nm = __ballot((int)newly);
      if (nm != 0ull && lane == (int)__builtin_ctzll(nm)) {
        int oi = b * NOBJ + (win >> 2);     // this lane is newly => win = cbx[j]
        if (atomicCAS(&used[oi], 0, 1) == 0) {
          int rr = atomicAdd(nrowsp, 1);
          rowobj[rr] = oi;
          remap[oi]  = rr;
        }
      }
    }
    pxwin[b * 16384 + y * 128 + x] = win;
  } else if (bid < ROLE_WIN + ROLE_G1) {
    // ---- role 1: H[r] = relu(Z[r] @ W1 + b1) -> bf16, original object order ----
    const int r = bid - ROLE_WIN;            // 0..539 = b*135 + obj
    if (t < ZW) u.zs[t] = Z[(size_t)r * ZW + t];
    __syncthreads();
    float a0 = b1[t], a1 = b1[t + 256];
#pragma unroll 8
    for (int k = 0; k < ZW; k++) {
      float z = u.zs[k];
      a0 += z * W1[(size_t)k * HIDN + t];
      a1 += z * W1[(size_t)k * HIDN + t + 256];
    }
    Hbf[(size_t)r * HIDN + t]       = f2bf(fmaxf(a0, 0.f));
    Hbf[(size_t)r * HIDN + t + 256] = f2bf(fmaxf(a1, 0.f));
  } else {
    // ---- role 2: W2 (512 x 12288 f32) -> W2T (12288 x 512 bf16) ----
    const int c  = bid - ROLE_WIN - ROLE_G1;
    const int n0 = (c % (NOUT / 64)) * 64;
    const int k0 = (c / (NOUT / 64)) * 64;
#pragma unroll
    for (int p = 0; p < 2; p++) {
      int kp = p * 16 + (t >> 4);        // k-pair 0..31
      int n4 = t & 15;
      int k  = k0 + kp * 2;
      float4 a = *(const float4*)&W2[(size_t)k * NOUT + n0 + n4 * 4];
      float4 b = *(const float4*)&W2[(size_t)(k + 1) * NOUT + n0 + n4 * 4];
      u.T[(n4*4 + 0) * 36 + kp] = (unsigned)f2bf(a.x) | ((unsigned)f2bf(b.x) << 16);
      u.T[(n4*4 + 1) * 36 + kp] = (unsigned)f2bf(a.y) | ((unsigned)f2bf(b.y) << 16);
      u.T[(n4*4 + 2) * 36 + kp] = (unsigned)f2bf(a.z) | ((unsigned)f2bf(b.z) << 16);
      u.T[(n4*4 + 3) * 36 + kp] = (unsigned)f2bf(a.w) | ((unsigned)f2bf(b.w) << 16);
    }
    __syncthreads();
#pragma unroll
    for (int p = 0; p < 2; p++) {
      int cc = p * 256 + t;
      int n = cc >> 3, ch = cc & 7;      // 8 chunks of 8 k (16B)
      uint4 v = *(const uint4*)&u.T[n * 36 + ch * 4];
      *(uint4*)&W2T[(size_t)(n0 + n) * HIDN + k0 + ch * 8] = v;
    }
  }
}

// ---------------------------------------------------------------------------
// K2: dec[row] = sigmoid(H[rowobj[row]] @ W2T^T + b2) for compact visible rows
// only.  bf16 MFMA 16x16x32, 128x128 tiles, 2-phase prefetch double-buffer.
// ---------------------------------------------------------------------------
__global__ __launch_bounds__(256) void k_gemm2_mfma(
    const unsigned short* __restrict__ Hbf,   // 540 x 512 bf16
    const unsigned short* __restrict__ W2T,   // 12288 x 512 bf16
    const float* __restrict__ b2,
    const int* __restrict__ nrowsp,
    const int* __restrict__ rowobj,
    float* __restrict__ dec)                  // 640 x 12288 f32 (compact rows)
{
  __shared__ unsigned short As[2][128 * 32];
  __shared__ unsigned short Bs[2][128 * 32];
  const int nr = *nrowsp;
  // XCD-aware bijective swizzle over the 480-block grid (480 = 8*60)
  int bid = (int)blockIdx.x;
  bid = (bid & 7) * 60 + (bid >> 3);
  const int m0 = (bid / 96) * 128;
  if (m0 >= nr) return;                       // prune dead m-tiles
  const int n0 = (bid % 96) * 128;

  const int t    = threadIdx.x;
  const int lane = t & 63, wv = t >> 6;
  const int wm = (wv & 1) * 64, wn = (wv >> 1) * 64;

  const int r0  = t >> 2;
  const int kc0 = (t & 3) ^ (r0 & 3);
  const int r1  = r0 + 64;
  const int kc1 = (t & 3) ^ (r1 & 3);

  const int ga0 = (m0 + r0 < nr) ? rowobj[m0 + r0] : 0;   // tail rows -> row 0 (unread)
  const int ga1 = (m0 + r1 < nr) ? rowobj[m0 + r1] : 0;
  const unsigned short* a0p = Hbf + (size_t)ga0 * HIDN + kc0 * 8;
  const unsigned short* a1p = Hbf + (size_t)ga1 * HIDN + kc1 * 8;
  const unsigned short* b0p = W2T + (size_t)(n0 + r0) * HIDN + kc0 * 8;
  const unsigned short* b1p = W2T + (size_t)(n0 + r1) * HIDN + kc1 * 8;

  const int fr = lane & 15;
  const int fj = lane >> 4;
  f32x4 acc[4][4] = {};

#define STAGE(buf, koff)                                                       \
  do {                                                                         \
    GLOAD_LDS16(a0p + (koff), &As[buf][t * 8]);                                \
    GLOAD_LDS16(a1p + (koff), &As[buf][(t + 256) * 8]);                        \
    GLOAD_LDS16(b0p + (koff), &Bs[buf][t * 8]);                                \
    GLOAD_LDS16(b1p + (koff), &Bs[buf][(t + 256) * 8]);                        \
  } while (0)

  STAGE(0, 0);
  __syncthreads();
  int cur = 0;
  for (int kt = 0; kt < HIDN / 32; ++kt) {
    if (kt < HIDN / 32 - 1) STAGE(cur ^ 1, (kt + 1) * 32);   // prefetch in flight
    bf16x8 av[4], bv[4];
#pragma unroll
    for (int mi = 0; mi < 4; mi++) {
      int row = wm + mi * 16 + fr;
      av[mi] = *(const bf16x8*)&As[cur][(row * 4 + (fj ^ (row & 3))) * 8];
    }
#pragma unroll
    for (int ni = 0; ni < 4; ni++) {
      int row = wn + ni * 16 + fr;
      bv[ni] = *(const bf16x8*)&Bs[cur][(row * 4 + (fj ^ (row & 3))) * 8];
    }
#pragma unroll
    for (int mi = 0; mi < 4; mi++)
#pragma unroll
      for (int ni = 0; ni < 4; ni++)
        acc[mi][ni] = __builtin_amdgcn_mfma_f32_16x16x32_bf16(av[mi], bv[ni], acc[mi][ni], 0, 0, 0);
    __syncthreads();   // drains prefetch (vmcnt) + guards LDS reuse
    cur ^= 1;
  }
#undef STAGE

#pragma unroll
  for (int ni = 0; ni < 4; ni++) {
    int col = n0 + wn + ni * 16 + fr;
    float bb = b2[col];
#pragma unroll
    for (int mi = 0; mi < 4; mi++) {
#pragma unroll
      for (int r = 0; r < 4; r++) {
        int row = m0 + wm + mi * 16 + fj * 4 + r;   // < 640, dec has 640 rows
        float v = acc[mi][ni][r] + bb;
        dec[(size_t)row * NOUT + col] = 1.0f / (1.0f + __expf(-v));
      }
    }
  }
}

// ---------------------------------------------------------------------------
// K3: light composite — winner is precomputed; recompute its fp64 taps
// (bit-identical math) and gather 12 floats from the compact dec row.
// ---------------------------------------------------------------------------
__global__ __launch_bounds__(256) void k_composite(
    const int* __restrict__ pxwin, const int* __restrict__ remap,
    const float* __restrict__ z_where, const float* __restrict__ dec,
    float* __restrict__ out)
{
#pragma clang fp contract(off)
  const int bid  = blockIdx.x;
  const int t    = threadIdx.x;
  const int b    = bid >> 6;
  const int tile = bid & 63;
  const int y = (tile >> 3) * 16 + (t >> 4);
  const int x = (tile & 7) * 16 + (t & 15);

  const int win = pxwin[b * 16384 + y * 128 + x];
  float o0 = 0.f, o1 = 0.f, o2 = 0.f;
  if (win >= 0) {
    const F4 p = *(const F4*)&z_where[((size_t)b * NBOX + win) * 4];
    const double step = 2.0 / 127.0;
    const double gx = (x == 127) ? 1.0 : ((double)x * step + (-1.0));
    const double gy = (y == 127) ? 1.0 : ((double)y * step + (-1.0));
    double w = fmax((double)p.z, 0.01);
    double h = fmax((double)p.w, 0.01);
    double tx = 2.0 * (double)p.x - 1.0;
    double ty = 2.0 * (double)p.y - 1.0;
    double u = (gx - tx) / w;
    double v = (gy - ty) / h;
    double px = (u + 1.0) * 0.5 * 63.0;
    double py = (v + 1.0) * 0.5 * 63.0;
    double fx = floor(px), fy = floor(py);
    double wx = px - fx, wy = py - fy;
    int x0 = (int)fx, y0 = (int)fy;
    int x1 = x0 + 1, y1 = y0 + 1;
    bool vx0 = (x0 >= 0) && (x0 < OBJS);
    bool vx1 = (x1 >= 0) && (x1 < OBJS);
    bool vy0 = (y0 >= 0) && (y0 < OBJS);
    bool vy1 = (y1 >= 0) && (y1 < OBJS);
    double w00 = (1.0 - wy) * (1.0 - wx);
    double w01 = (1.0 - wy) * wx;
    double w10 = wy * (1.0 - wx);
    double w11 = wy * wx;
    bool c00 = vy0 && vx0 && (w00 > 0.0);
    bool c01 = vy0 && vx1 && (w01 > 0.0);
    bool c10 = vy1 && vx0 && (w10 > 0.0);
    bool c11 = vy1 && vx1 && (w11 > 0.0);
    const int row = remap[b * NOBJ + (win >> 2)];
    const float* g = dec + (size_t)row * NOUT;
    double s0 = 0.0, s1 = 0.0, s2 = 0.0;
    if (c00) { int o = y0*64 + x0; s0 += g[o]*w00; s1 += g[4096+o]*w00; s2 += g[8192+o]*w00; }
    if (c01) { int o = y0*64 + x1; s0 += g[o]*w01; s1 += g[4096+o]*w01; s2 += g[8192+o]*w01; }
    if (c10) { int o = y1*64 + x0; s0 += g[o]*w10; s1 += g[4096+o]*w10; s2 += g[8192+o]*w10; }
    if (c11) { int o = y1*64 + x1; s0 += g[o]*w11; s1 += g[4096+o]*w11; s2 += g[8192+o]*w11; }
    o0 = (float)s0; o1 = (float)s1; o2 = (float)s2;
  }
  const int ob = b * 3 * 16384 + y * 128 + x;    // (B,3,128,128)
  out[ob]         = o0;
  out[ob + 16384] = o1;
  out[ob + 32768] = o2;
}

// ---------------------------------------------------------------------------
extern "C" void kernel_launch(void* const* d_in, const int* in_sizes, int n_in,
                              void* d_out, int out_size, void* d_ws, size_t ws_size,
                              hipStream_t stream) {
  (void)in_sizes; (void)n_in; (void)out_size; (void)ws_size;
  const float* z_what    = (const float*)d_in[0];
  const float* z_where   = (const float*)d_in[1];
  const float* z_depth   = (const float*)d_in[2];
  const float* W1        = (const float*)d_in[3];
  const float* b1        = (const float*)d_in[4];
  const float* W2        = (const float*)d_in[5];
  const float* b2        = (const float*)d_in[6];
  const int*   z_present = (const int*)d_in[7];
  float* out = (float*)d_out;
  char* ws = (char*)d_ws;

  int*            nrowsp = (int*)(ws + OFF_NROWS);
  int*            used   = (int*)(ws + OFF_USED);
  int*            remap  = (int*)(ws + OFF_REMAP);
  int*            rowobj = (int*)(ws + OFF_ROWOBJ);
  int*            pxwin  = (int*)(ws + OFF_PXWIN);
  unsigned short* Hbf    = (unsigned short*)(ws + OFF_HBF);
  unsigned short* W2T    = (unsigned short*)(ws + OFF_W2T);
  float*          dec    = (float*)(ws + OFF_DEC);

  // zero nrows + used[] (workspace is poisoned between iterations)
  hipMemsetAsync(ws + OFF_NROWS, 0, 2560, stream);

  k_pre<<<dim3(PRE_BLOCKS), dim3(256), 0, stream>>>(
      z_depth, z_where, z_present, z_what, W1, b1, W2,
      nrowsp, used, remap, rowobj, pxwin, Hbf, W2T);
  k_gemm2_mfma<<<dim3((NOUT / 128) * 5), dim3(256), 0, stream>>>(
      Hbf, W2T, b2, nrowsp, rowobj, dec);
  k_composite<<<dim3(256), dim3(256), 0, stream>>>(pxwin, remap, z_where, dec, out);
}

// Round 4
// 118.835 us; speedup vs baseline: 1.2723x; 1.0383x over previous
//
#include <hip/hip_runtime.h>
#include <hip/hip_bf16.h>
#include <math.h>

#define NBOX  540      // total boxes per batch
#define NOBJ  135      // unique objects per batch
#define ZW    64
#define HIDN  512
#define NOUT  12288    // 3*64*64
#define OBJS  64
#define BATCH 4

// fused K1 block roles: [winner 256 | gemm1 540]  (W2 cvt now fused into gemm2)
#define ROLE_WIN   256
#define ROLE_G1    540
#define PRE_BLOCKS (ROLE_WIN + ROLE_G1)

// gemm2 grid: 384 n-tiles (32 cols) x 5 m-tiles (128 rows), m is FAST dim so
// active (m0=0) blocks spread across XCDs under the swizzle.
#define G2_BLOCKS  1920

// workspace layout (bytes), 256-aligned (W2T region retired, offsets kept)
#define OFF_NROWS  0u          // int
#define OFF_USED   256u        // int[540]   -> 2416
#define OFF_REMAP  2560u       // int[540]   -> 4720
#define OFF_ROWOBJ 4864u       // int[640]   -> 7424
#define OFF_PXWIN  7680u       // int[65536] -> 269824
#define OFF_HBF    269824u     // ushort 640*512 = 655360 -> 925184
#define OFF_DEC    13508096u   // float 640*12288 = 31457280 -> ~45 MB

typedef short  bf16x8 __attribute__((ext_vector_type(8)));
typedef float  f32x4  __attribute__((ext_vector_type(4)));

struct F4 { float x, y, z, w; };   // POD float4 (union-safe)

#define GLOAD_LDS16(gp, lp)                                                    \
  __builtin_amdgcn_global_load_lds(                                            \
      (const __attribute__((address_space(1))) void*)(gp),                     \
      (__attribute__((address_space(3))) void*)(lp), 16, 0, 0)

__device__ __forceinline__ unsigned short f2bf(float x) {
  __hip_bfloat16 h = __float2bfloat16(x);
  return *(unsigned short*)&h;
}

// ---------------------------------------------------------------------------
// K1: fused {painter visibility search | gemm1}
// Winner role: per 16x16 px tile: bitonic-sort the batch's 135 depths, compact
// present boxes in depth order into LDS with (a) conservative integer pixel
// bboxes (wave-uniform skip) and (b) f32 center/half-width prefilter with
// exact fp64 fallback for borderline candidates (decisions bit-identical to
// the reference predicate).
// ---------------------------------------------------------------------------
__global__ __launch_bounds__(256) void k_pre(
    const float* __restrict__ z_depth,   // B*135
    const float* __restrict__ z_where,   // B*540*4
    const int*   __restrict__ z_present, // B*540
    const float* __restrict__ Z,         // B*135*64 z_what
    const float* __restrict__ W1,        // 64*512
    const float* __restrict__ b1,        // 512
    int* __restrict__ nrowsp,            // compact visible-row count (pre-zeroed)
    int* __restrict__ used,              // int[540] (pre-zeroed)
    int* __restrict__ remap,             // (b*135+obj) -> compact row
    int* __restrict__ rowobj,            // compact row -> (b*135+obj)
    int* __restrict__ pxwin,             // per-pixel winning box (orig id) or -1
    unsigned short* __restrict__ Hbf)    // 540*512 bf16
{
  __shared__ union ShMem {
    struct {
      unsigned long long keys[256];   // 2048
      F4       cf[NBOX];              // 8640  f32 {tx, ty, rx, ry} per candidate
      unsigned cbb[NBOX];             // 2160  packed bbox xlo|xhi|ylo|yhi
      int      cbx[NBOX];             // 2160  original box index
    } win;                            // 15008
    float    zs[ZW];                  // 256   (gemm1 role)
  } u;
  __shared__ int wsums[4], woff[4], nPs;

  const int bid = blockIdx.x;
  const int t   = threadIdx.x;

  if (bid < ROLE_WIN) {
    // ---- role 0: visibility search ----
#pragma clang fp contract(off)
    const int b    = bid >> 6;
    const int tile = bid & 63;
    const int lane = t & 63, wv = t >> 6;
    const int y = (tile >> 3) * 16 + (t >> 4);
    const int x = (tile & 7) * 16 + (t & 15);

    unsigned long long key = ~0ull;
    if (t < NOBJ) {
      unsigned uu = __float_as_uint(z_depth[b * NOBJ + t]);
      uu = (uu & 0x80000000u) ? ~uu : (uu | 0x80000000u);     // orderable uint
      key = ((unsigned long long)(~uu) << 32) | (unsigned)t;  // asc == depth desc
    }
    u.win.keys[t] = key;
    __syncthreads();
    for (int k = 2; k <= 256; k <<= 1) {
      for (int j = k >> 1; j > 0; j >>= 1) {
        int ixj = t ^ j;
        if (ixj > t) {
          unsigned long long a = u.win.keys[t], c = u.win.keys[ixj];
          bool asc = (t & k) == 0;
          if (asc ? (a > c) : (a < c)) { u.win.keys[t] = c; u.win.keys[ixj] = a; }
        }
        __syncthreads();
      }
    }

    // compact present boxes (sorted order) + bboxes + f32 prefilter params
    int boxq[3], presq[3], cnt = 0;
#pragma unroll
    for (int q = 0; q < 3; q++) {
      int e = 3 * t + q;
      presq[q] = 0; boxq[q] = 0;
      if (e < NBOX) {
        int o  = (int)(u.win.keys[e >> 2] & 0xFFFFFFFFull);
        int bx = o * 4 + (e & 3);
        boxq[q]  = bx;
        presq[q] = (z_present[b * NBOX + bx] != 0) ? 1 : 0;
        cnt += presq[q];
      }
    }
    int incl = cnt;
#pragma unroll
    for (int o = 1; o < 64; o <<= 1) {
      int vprev = __shfl_up(incl, o, 64);
      if (lane >= o) incl += vprev;
    }
    if (lane == 63) wsums[wv] = incl;
    __syncthreads();
    if (t == 0) {
      int a = 0;
#pragma unroll
      for (int i = 0; i < 4; i++) { woff[i] = a; a += wsums[i]; }
      nPs = a;
    }
    __syncthreads();
    int slot = woff[wv] + incl - cnt;
#pragma unroll
    for (int q = 0; q < 3; q++) {
      if (presq[q]) {
        int bx = boxq[q];
        F4 p = *(const F4*)&z_where[((size_t)b * NBOX + bx) * 4];
        double w  = fmax((double)p.z, 0.01);
        double h  = fmax((double)p.w, 0.01);
        double tx = 2.0 * (double)p.x - 1.0;
        double ty = 2.0 * (double)p.y - 1.0;
        const double S = 65.0 / 63.0;       // coverage iff |gx-tx| < w*S (real)
        int xlo = (int)floor((tx - w * S + 1.0) * 63.5) - 1;   // 63.5 = 1/step
        int xhi = (int)floor((tx + w * S + 1.0) * 63.5) + 2;
        int ylo = (int)floor((ty - h * S + 1.0) * 63.5) - 1;
        int yhi = (int)floor((ty + h * S + 1.0) * 63.5) + 2;
        xlo = max(xlo, 0); ylo = max(ylo, 0);
        xhi = min(xhi, 127); yhi = min(yhi, 127);
        unsigned bb = (xhi < xlo || yhi < ylo) ? 0xFFu   // sentinel: always skip
                    : ((unsigned)xlo | ((unsigned)xhi << 8) |
                       ((unsigned)ylo << 16) | ((unsigned)yhi << 24));
        F4 f;
        f.x = (float)tx; f.y = (float)ty;
        f.z = (float)(w * S); f.w = (float)(h * S);
        u.win.cf[slot]  = f;
        u.win.cbb[slot] = bb;
        u.win.cbx[slot] = bx;
        slot++;
      }
    }
    __syncthreads();

    const int nP = nPs;
    const double step = 2.0 / 127.0;
    const double gx = (x == 127) ? 1.0 : ((double)x * step + (-1.0));
    const double gy = (y == 127) ? 1.0 : ((double)y * step + (-1.0));
    const float gxf = (float)gx, gyf = (float)gy;
    const int tx0 = (tile & 7) * 16, tx1 = tx0 + 15;
    const int wy0 = (tile >> 3) * 16 + wv * 4, wy1 = wy0 + 3;  // wave's 16x4 strip

    bool done = false;
    int  win  = -1;
    for (int j = 0; j < nP; j++) {
      if (__all((int)done)) break;
      unsigned bb = u.win.cbb[j];
      int bxlo = (int)(bb & 255u),         bxhi = (int)((bb >> 8) & 255u);
      int bylo = (int)((bb >> 16) & 255u), byhi = (int)(bb >> 24);
      if (bxhi < tx0 || bxlo > tx1 || byhi < wy0 || bylo > wy1) continue;
      bool newly = false;
      if (!done) {
        F4 f = u.win.cf[j];
        float dx = fabsf(gxf - f.x), dy = fabsf(gyf - f.y);
        // conservative margins: f32 pipeline error <= ~5e-7, band = 1e-4 rel + 2e-6 abs
        bool in_lo = (dx < f.z * 0.9999f - 2e-6f) & (dy < f.w * 0.9999f - 2e-6f);
        bool in_hi = (dx < f.z * 1.0001f + 2e-6f) & (dy < f.w * 1.0001f + 2e-6f);
        bool cov;
        if (in_lo) {
          cov = true;                       // definitely covered
        } else if (!in_hi) {
          cov = false;                      // definitely not covered
        } else {
          // borderline (~1e-4 prob): exact fp64 sequence, bit-identical to ref
          F4 p = *(const F4*)&z_where[((size_t)b * NBOX + u.win.cbx[j]) * 4];
          double w  = fmax((double)p.z, 0.01);
          double h  = fmax((double)p.w, 0.01);
          double tx = 2.0 * (double)p.x - 1.0;
          double ty = 2.0 * (double)p.y - 1.0;
          double uu = (gx - tx) / w;
          double vv = (gy - ty) / h;
          double px = (uu + 1.0) * 0.5 * 63.0;
          double py = (vv + 1.0) * 0.5 * 63.0;
          cov = (px > -1.0) && (px < 64.0) && (py > -1.0) && (py < 64.0);
        }
        if (cov) { win = u.win.cbx[j]; done = true; newly = true; }
      }
      unsigned long long nm = __ballot((int)newly);
      if (nm != 0ull && lane == (int)__builtin_ctzll(nm)) {
        int oi = b * NOBJ + (win >> 2);     // this lane is newly => win = cbx[j]
        if (atomicCAS(&used[oi], 0, 1) == 0) {
          int rr = atomicAdd(nrowsp, 1);
          rowobj[rr] = oi;
          remap[oi]  = rr;
        }
      }
    }
    pxwin[b * 16384 + y * 128 + x] = win;
  } else {
    // ---- role 1: H[r] = relu(Z[r] @ W1 + b1) -> bf16, original object order ----
    const int r = bid - ROLE_WIN;            // 0..539 = b*135 + obj
    if (t < ZW) u.zs[t] = Z[(size_t)r * ZW + t];
    __syncthreads();
    float a0 = b1[t], a1 = b1[t + 256];
#pragma unroll 8
    for (int k = 0; k < ZW; k++) {
      float z = u.zs[k];
      a0 += z * W1[(size_t)k * HIDN + t];
      a1 += z * W1[(size_t)k * HIDN + t + 256];
    }
    Hbf[(size_t)r * HIDN + t]       = f2bf(fmaxf(a0, 0.f));
    Hbf[(size_t)r * HIDN + t + 256] = f2bf(fmaxf(a1, 0.f));
  }
}

// ---------------------------------------------------------------------------
// K2: dec[row] = sigmoid(H[rowobj[row]] @ W2^T + b2) for compact visible rows.
// W2 is read DIRECTLY as f32 (32-col slices) and converted to bf16 in-register
// (same RNE f2bf as the old cvt role -> dec bit-identical).  Tiles 128m x 32n,
// bf16 MFMA 16x16x32, double-buffered; 384 active blocks at nr<=128 so the
// 25 MB W2 stream spreads across all CUs.
// ---------------------------------------------------------------------------
__global__ __launch_bounds__(256) void k_gemm2_mfma(
    const unsigned short* __restrict__ Hbf,   // 540 x 512 bf16
    const float* __restrict__ W2,             // 512 x 12288 f32
    const float* __restrict__ b2,
    const int* __restrict__ nrowsp,
    const int* __restrict__ rowobj,
    float* __restrict__ dec)                  // 640 x 12288 f32 (compact rows)
{
  __shared__ unsigned short As[2][128 * 32];  // A tile, bf16, swizzled chunks
  __shared__ float          BsF[2][32 * 32];  // B tile, f32, [k][n] linear
  const int nr = *nrowsp;
  // XCD-aware bijective swizzle over the 1920-block grid (1920 = 8*240)
  int bid = (int)blockIdx.x;
  bid = (bid & 7) * 240 + (bid >> 3);
  const int m0 = (bid % 5) * 128;             // m fast -> active blocks spread
  if (m0 >= nr) return;
  const int n0 = (bid / 5) * 32;

  const int t    = threadIdx.x;
  const int lane = t & 63, wv = t >> 6;
  const int wm = (wv & 1) * 64;               // wave: 64 rows x 16 cols
  const int wn = (wv >> 1) * 16;

  const int r0  = t >> 2;
  const int kc0 = (t & 3) ^ (r0 & 3);
  const int r1  = r0 + 64;
  const int kc1 = (t & 3) ^ (r1 & 3);

  const int ga0 = (m0 + r0 < nr) ? rowobj[m0 + r0] : 0;   // tail rows -> row 0 (unread)
  const int ga1 = (m0 + r1 < nr) ? rowobj[m0 + r1] : 0;
  const unsigned short* a0p = Hbf + (size_t)ga0 * HIDN + kc0 * 8;
  const unsigned short* a1p = Hbf + (size_t)ga1 * HIDN + kc1 * 8;
  // B staging: thread t loads W2[k0 + (t>>3)][n0 + (t&7)*4 .. +3] (16 B) to
  // BsF[t*4] (linear, matches global_load_lds lane*16 rule).
  const float* bp = W2 + (size_t)(t >> 3) * NOUT + n0 + (t & 7) * 4;

  const int fr = lane & 15;
  const int fj = lane >> 4;
  f32x4 acc[4] = {};

#define STAGE(buf, kt)                                                         \
  do {                                                                         \
    GLOAD_LDS16(a0p + (kt) * 32, &As[buf][t * 8]);                             \
    GLOAD_LDS16(a1p + (kt) * 32, &As[buf][(t + 256) * 8]);                     \
    GLOAD_LDS16(bp + (size_t)(kt) * 32 * NOUT, &BsF[buf][t * 4]);              \
  } while (0)

  STAGE(0, 0);
  __syncthreads();
  int cur = 0;
  for (int kt = 0; kt < HIDN / 32; ++kt) {
    if (kt < HIDN / 32 - 1) STAGE(cur ^ 1, kt + 1);   // prefetch in flight
    bf16x8 av[4];
#pragma unroll
    for (int mi = 0; mi < 4; mi++) {
      int row = wm + mi * 16 + fr;
      av[mi] = *(const bf16x8*)&As[cur][(row * 4 + (fj ^ (row & 3))) * 8];
    }
    bf16x8 bv;
#pragma unroll
    for (int j = 0; j < 8; j++)
      bv[j] = (short)f2bf(BsF[cur][(fj * 8 + j) * 32 + wn + fr]);
#pragma unroll
    for (int mi = 0; mi < 4; mi++)
      acc[mi] = __builtin_amdgcn_mfma_f32_16x16x32_bf16(av[mi], bv, acc[mi], 0, 0, 0);
    __syncthreads();   // drains prefetch (vmcnt) + guards LDS reuse
    cur ^= 1;
  }
#undef STAGE

  const int col = n0 + wn + fr;
  const float bb = b2[col];
#pragma unroll
  for (int mi = 0; mi < 4; mi++) {
#pragma unroll
    for (int r = 0; r < 4; r++) {
      int row = m0 + wm + mi * 16 + fj * 4 + r;   // < 640, dec has 640 rows
      float v = acc[mi][r] + bb;
      dec[(size_t)row * NOUT + col] = 1.0f / (1.0f + __expf(-v));
    }
  }
}

// ---------------------------------------------------------------------------
// K3: light composite — winner is precomputed; recompute its fp64 taps
// (bit-identical math) and gather 12 floats from the compact dec row.
// ---------------------------------------------------------------------------
__global__ __launch_bounds__(256) void k_composite(
    const int* __restrict__ pxwin, const int* __restrict__ remap,
    const float* __restrict__ z_where, const float* __restrict__ dec,
    float* __restrict__ out)
{
#pragma clang fp contract(off)
  const int bid  = blockIdx.x;
  const int t    = threadIdx.x;
  const int b    = bid >> 6;
  const int tile = bid & 63;
  const int y = (tile >> 3) * 16 + (t >> 4);
  const int x = (tile & 7) * 16 + (t & 15);

  const int win = pxwin[b * 16384 + y * 128 + x];
  float o0 = 0.f, o1 = 0.f, o2 = 0.f;
  if (win >= 0) {
    const F4 p = *(const F4*)&z_where[((size_t)b * NBOX + win) * 4];
    const double step = 2.0 / 127.0;
    const double gx = (x == 127) ? 1.0 : ((double)x * step + (-1.0));
    const double gy = (y == 127) ? 1.0 : ((double)y * step + (-1.0));
    double w = fmax((double)p.z, 0.01);
    double h = fmax((double)p.w, 0.01);
    double tx = 2.0 * (double)p.x - 1.0;
    double ty = 2.0 * (double)p.y - 1.0;
    double u = (gx - tx) / w;
    double v = (gy - ty) / h;
    double px = (u + 1.0) * 0.5 * 63.0;
    double py = (v + 1.0) * 0.5 * 63.0;
    double fx = floor(px), fy = floor(py);
    double wx = px - fx, wy = py - fy;
    int x0 = (int)fx, y0 = (int)fy;
    int x1 = x0 + 1, y1 = y0 + 1;
    bool vx0 = (x0 >= 0) && (x0 < OBJS);
    bool vx1 = (x1 >= 0) && (x1 < OBJS);
    bool vy0 = (y0 >= 0) && (y0 < OBJS);
    bool vy1 = (y1 >= 0) && (y1 < OBJS);
    double w00 = (1.0 - wy) * (1.0 - wx);
    double w01 = (1.0 - wy) * wx;
    double w10 = wy * (1.0 - wx);
    double w11 = wy * wx;
    bool c00 = vy0 && vx0 && (w00 > 0.0);
    bool c01 = vy0 && vx1 && (w01 > 0.0);
    bool c10 = vy1 && vx0 && (w10 > 0.0);
    bool c11 = vy1 && vx1 && (w11 > 0.0);
    const int row = remap[b * NOBJ + (win >> 2)];
    const float* g = dec + (size_t)row * NOUT;
    double s0 = 0.0, s1 = 0.0, s2 = 0.0;
    if (c00) { int o = y0*64 + x0; s0 += g[o]*w00; s1 += g[4096+o]*w00; s2 += g[8192+o]*w00; }
    if (c01) { int o = y0*64 + x1; s0 += g[o]*w01; s1 += g[4096+o]*w01; s2 += g[8192+o]*w01; }
    if (c10) { int o = y1*64 + x0; s0 += g[o]*w10; s1 += g[4096+o]*w10; s2 += g[8192+o]*w10; }
    if (c11) { int o = y1*64 + x1; s0 += g[o]*w11; s1 += g[4096+o]*w11; s2 += g[8192+o]*w11; }
    o0 = (float)s0; o1 = (float)s1; o2 = (float)s2;
  }
  const int ob = b * 3 * 16384 + y * 128 + x;    // (B,3,128,128)
  out[ob]         = o0;
  out[ob + 16384] = o1;
  out[ob + 32768] = o2;
}

// ---------------------------------------------------------------------------
extern "C" void kernel_launch(void* const* d_in, const int* in_sizes, int n_in,
                              void* d_out, int out_size, void* d_ws, size_t ws_size,
                              hipStream_t stream) {
  (void)in_sizes; (void)n_in; (void)out_size; (void)ws_size;
  const float* z_what    = (const float*)d_in[0];
  const float* z_where   = (const float*)d_in[1];
  const float* z_depth   = (const float*)d_in[2];
  const float* W1        = (const float*)d_in[3];
  const float* b1        = (const float*)d_in[4];
  const float* W2        = (const float*)d_in[5];
  const float* b2        = (const float*)d_in[6];
  const int*   z_present = (const int*)d_in[7];
  float* out = (float*)d_out;
  char* ws = (char*)d_ws;

  int*            nrowsp = (int*)(ws + OFF_NROWS);
  int*            used   = (int*)(ws + OFF_USED);
  int*            remap  = (int*)(ws + OFF_REMAP);
  int*            rowobj = (int*)(ws + OFF_ROWOBJ);
  int*            pxwin  = (int*)(ws + OFF_PXWIN);
  unsigned short* Hbf    = (unsigned short*)(ws + OFF_HBF);
  float*          dec    = (float*)(ws + OFF_DEC);

  // zero nrows + used[] (workspace is poisoned between iterations)
  hipMemsetAsync(ws + OFF_NROWS, 0, 2560, stream);

  k_pre<<<dim3(PRE_BLOCKS), dim3(256), 0, stream>>>(
      z_depth, z_where, z_present, z_what, W1, b1,
      nrowsp, used, remap, rowobj, pxwin, Hbf);
  k_gemm2_mfma<<<dim3(G2_BLOCKS), dim3(256), 0, stream>>>(
      Hbf, W2, b2, nrowsp, rowobj, dec);
  k_composite<<<dim3(256), dim3(256), 0, stream>>>(pxwin, remap, z_where, dec, out);
}

// Round 5
// 113.091 us; speedup vs baseline: 1.3370x; 1.0508x over previous
//
#include <hip/hip_runtime.h>
#include <hip/hip_bf16.h>
#include <math.h>

#define NBOX  540      // total boxes per batch
#define NOBJ  135      // unique objects per batch
#define ZW    64
#define HIDN  512
#define NOUT  12288    // 3*64*64
#define OBJS  64
#define BATCH 4

// fused K1 block roles: [winner 256 | gemm1 135 (4 rows/block)]
#define ROLE_WIN   256
#define ROLE_G1    135
#define PRE_BLOCKS (ROLE_WIN + ROLE_G1)

// gemm2 grid: 384 n-tiles (32 cols) x 5 m-tiles (128 rows), m is FAST dim so
// active (m0=0) blocks spread across XCDs under the swizzle.
#define G2_BLOCKS  1920
#define BK   64
#define NK   (HIDN / BK)     // 8 K-phases

// workspace layout (bytes), 256-aligned
#define OFF_NROWS  0u          // int
#define OFF_USED   256u        // int[540]   -> 2416
#define OFF_REMAP  2560u       // int[540]   -> 4720
#define OFF_ROWOBJ 4864u       // int[640]   -> 7424
#define OFF_PXWIN  7680u       // int[65536] -> 269824
#define OFF_HBF    269824u     // ushort 640*512 = 655360 -> 925184
#define OFF_DEC    13508096u   // float 640*12288 = 31457280 -> ~45 MB

typedef short  bf16x8 __attribute__((ext_vector_type(8)));
typedef float  f32x4  __attribute__((ext_vector_type(4)));

struct F4 { float x, y, z, w; };   // POD float4 (union-safe)

#define GLOAD_LDS16(gp, lp)                                                    \
  __builtin_amdgcn_global_load_lds(                                            \
      (const __attribute__((address_space(1))) void*)(gp),                     \
      (__attribute__((address_space(3))) void*)(lp), 16, 0, 0)

__device__ __forceinline__ unsigned short f2bf(float x) {
  __hip_bfloat16 h = __float2bfloat16(x);
  return *(unsigned short*)&h;
}

// ---------------------------------------------------------------------------
// K1: fused {painter visibility search | gemm1}
// Winner role: rank-sort (O(n^2), barrier-free) the batch's 135 depths,
// compact present boxes in depth order into LDS with conservative integer
// bboxes (wave-uniform skip) + f32 prefilter with exact fp64 fallback.
// All coverage decisions bit-identical to the reference predicate.
// ---------------------------------------------------------------------------
__global__ __launch_bounds__(256) void k_pre(
    const float* __restrict__ z_depth,   // B*135
    const float* __restrict__ z_where,   // B*540*4
    const int*   __restrict__ z_present, // B*540
    const float* __restrict__ Z,         // B*135*64 z_what
    const float* __restrict__ W1,        // 64*512
    const float* __restrict__ b1,        // 512
    int* __restrict__ nrowsp,            // compact visible-row count (pre-zeroed)
    int* __restrict__ used,              // int[540] (pre-zeroed)
    int* __restrict__ remap,             // (b*135+obj) -> compact row
    int* __restrict__ rowobj,            // compact row -> (b*135+obj)
    int* __restrict__ pxwin,             // per-pixel winning box (orig id) or -1
    unsigned short* __restrict__ Hbf)    // 540*512 bf16
{
  __shared__ union ShMem {
    struct {
      unsigned su[136];               // 544   orderable depth keys
      int      sobj[136];             // 544   rank -> obj
      F4       cf[NBOX];              // 8640  f32 {tx, ty, rx, ry} per candidate
      unsigned cbb[NBOX];             // 2160  packed bbox xlo|xhi|ylo|yhi
      int      cbx[NBOX];             // 2160  original box index
    } win;                            // ~14 KB
    float    zs[4][ZW];               // 1024  (gemm1 role, 4 rows)
  } u;
  __shared__ int wsums[4], woff[4], nPs;

  const int bid = blockIdx.x;
  const int t   = threadIdx.x;

  if (bid < ROLE_WIN) {
    // ---- role 0: visibility search ----
#pragma clang fp contract(off)
    const int b    = bid >> 6;
    const int tile = bid & 63;
    const int lane = t & 63, wv = t >> 6;
    const int y = (tile >> 3) * 16 + (t >> 4);
    const int x = (tile & 7) * 16 + (t & 15);

    // O(n^2) stable rank sort: asc by (~u, obj) == depth desc, ties obj asc
    if (t < NOBJ) {
      unsigned uu = __float_as_uint(z_depth[b * NOBJ + t]);
      uu = (uu & 0x80000000u) ? ~uu : (uu | 0x80000000u);     // orderable uint
      u.win.su[t] = uu;
    }
    __syncthreads();
    if (t < NOBJ) {
      const unsigned mykey = u.win.su[t];
      int r = 0;
      for (int j = 0; j < NOBJ; j++) {
        unsigned kj = u.win.su[j];
        r += (int)((kj > mykey) || (kj == mykey && j < t));
      }
      u.win.sobj[r] = t;
    }
    __syncthreads();

    // compact present boxes (sorted order) + bboxes + f32 prefilter params
    int boxq[3], presq[3], cnt = 0;
#pragma unroll
    for (int q = 0; q < 3; q++) {
      int e = 3 * t + q;
      presq[q] = 0; boxq[q] = 0;
      if (e < NBOX) {
        int o  = u.win.sobj[e >> 2];
        int bx = o * 4 + (e & 3);
        boxq[q]  = bx;
        presq[q] = (z_present[b * NBOX + bx] != 0) ? 1 : 0;
        cnt += presq[q];
      }
    }
    int incl = cnt;
#pragma unroll
    for (int o = 1; o < 64; o <<= 1) {
      int vprev = __shfl_up(incl, o, 64);
      if (lane >= o) incl += vprev;
    }
    if (lane == 63) wsums[wv] = incl;
    __syncthreads();
    if (t == 0) {
      int a = 0;
#pragma unroll
      for (int i = 0; i < 4; i++) { woff[i] = a; a += wsums[i]; }
      nPs = a;
    }
    __syncthreads();
    int slot = woff[wv] + incl - cnt;
#pragma unroll
    for (int q = 0; q < 3; q++) {
      if (presq[q]) {
        int bx = boxq[q];
        F4 p = *(const F4*)&z_where[((size_t)b * NBOX + bx) * 4];
        double w  = fmax((double)p.z, 0.01);
        double h  = fmax((double)p.w, 0.01);
        double tx = 2.0 * (double)p.x - 1.0;
        double ty = 2.0 * (double)p.y - 1.0;
        const double S = 65.0 / 63.0;       // coverage iff |gx-tx| < w*S (real)
        int xlo = (int)floor((tx - w * S + 1.0) * 63.5) - 1;   // 63.5 = 1/step
        int xhi = (int)floor((tx + w * S + 1.0) * 63.5) + 2;
        int ylo = (int)floor((ty - h * S + 1.0) * 63.5) - 1;
        int yhi = (int)floor((ty + h * S + 1.0) * 63.5) + 2;
        xlo = max(xlo, 0); ylo = max(ylo, 0);
        xhi = min(xhi, 127); yhi = min(yhi, 127);
        unsigned bb = (xhi < xlo || yhi < ylo) ? 0xFFu   // sentinel: always skip
                    : ((unsigned)xlo | ((unsigned)xhi << 8) |
                       ((unsigned)ylo << 16) | ((unsigned)yhi << 24));
        F4 f;
        f.x = (float)tx; f.y = (float)ty;
        f.z = (float)(w * S); f.w = (float)(h * S);
        u.win.cf[slot]  = f;
        u.win.cbb[slot] = bb;
        u.win.cbx[slot] = bx;
        slot++;
      }
    }
    __syncthreads();

    const int nP = nPs;
    const double step = 2.0 / 127.0;
    const double gx = (x == 127) ? 1.0 : ((double)x * step + (-1.0));
    const double gy = (y == 127) ? 1.0 : ((double)y * step + (-1.0));
    const float gxf = (float)gx, gyf = (float)gy;
    const int tx0 = (tile & 7) * 16, tx1 = tx0 + 15;
    const int wy0 = (tile >> 3) * 16 + wv * 4, wy1 = wy0 + 3;  // wave's 16x4 strip

    bool done = false;
    int  win  = -1;
    for (int j = 0; j < nP; j++) {
      if (__all((int)done)) break;
      unsigned bb = u.win.cbb[j];
      int bxlo = (int)(bb & 255u),         bxhi = (int)((bb >> 8) & 255u);
      int bylo = (int)((bb >> 16) & 255u), byhi = (int)(bb >> 24);
      if (bxhi < tx0 || bxlo > tx1 || byhi < wy0 || bylo > wy1) continue;
      bool newly = false;
      if (!done) {
        F4 f = u.win.cf[j];
        float dx = fabsf(gxf - f.x), dy = fabsf(gyf - f.y);
        // conservative margins: f32 pipeline error <= ~5e-7, band = 1e-4 rel + 2e-6 abs
        bool in_lo = (dx < f.z * 0.9999f - 2e-6f) & (dy < f.w * 0.9999f - 2e-6f);
        bool in_hi = (dx < f.z * 1.0001f + 2e-6f) & (dy < f.w * 1.0001f + 2e-6f);
        bool cov;
        if (in_lo) {
          cov = true;                       // definitely covered
        } else if (!in_hi) {
          cov = false;                      // definitely not covered
        } else {
          // borderline (~1e-4 prob): exact fp64 sequence, bit-identical to ref
          F4 p = *(const F4*)&z_where[((size_t)b * NBOX + u.win.cbx[j]) * 4];
          double w  = fmax((double)p.z, 0.01);
          double h  = fmax((double)p.w, 0.01);
          double tx = 2.0 * (double)p.x - 1.0;
          double ty = 2.0 * (double)p.y - 1.0;
          double uu = (gx - tx) / w;
          double vv = (gy - ty) / h;
          double px = (uu + 1.0) * 0.5 * 63.0;
          double py = (vv + 1.0) * 0.5 * 63.0;
          cov = (px > -1.0) && (px < 64.0) && (py > -1.0) && (py < 64.0);
        }
        if (cov) { win = u.win.cbx[j]; done = true; newly = true; }
      }
      unsigned long long nm = __ballot((int)newly);
      if (nm != 0ull && lane == (int)__builtin_ctzll(nm)) {
        int oi = b * NOBJ + (win >> 2);     // this lane is newly => win = cbx[j]
        if (atomicCAS(&used[oi], 0, 1) == 0) {
          int rr = atomicAdd(nrowsp, 1);
          rowobj[rr] = oi;
          remap[oi]  = rr;
        }
      }
    }
    pxwin[b * 16384 + y * 128 + x] = win;
  } else {
    // ---- role 1: H[r] = relu(Z[r] @ W1 + b1) -> bf16, 4 rows per block ----
    const int r0 = (bid - ROLE_WIN) * 4;     // rows r0..r0+3 (= b*135 + obj)
    u.zs[t >> 6][t & 63] = Z[(size_t)(r0 + (t >> 6)) * ZW + (t & 63)];
    __syncthreads();
    float a[4][2];
#pragma unroll
    for (int r = 0; r < 4; r++) { a[r][0] = b1[t]; a[r][1] = b1[t + 256]; }
#pragma unroll
    for (int k4 = 0; k4 < 16; k4++) {
      float4 zq[4];
#pragma unroll
      for (int r = 0; r < 4; r++) zq[r] = *(const float4*)&u.zs[r][k4 * 4];
#pragma unroll
      for (int kk = 0; kk < 4; kk++) {
        int k = k4 * 4 + kk;
        float w0 = W1[(size_t)k * HIDN + t];
        float w1 = W1[(size_t)k * HIDN + t + 256];
#pragma unroll
        for (int r = 0; r < 4; r++) {
          float z = ((const float*)&zq[r])[kk];
          a[r][0] += z * w0;
          a[r][1] += z * w1;
        }
      }
    }
#pragma unroll
    for (int r = 0; r < 4; r++) {
      Hbf[(size_t)(r0 + r) * HIDN + t]       = f2bf(fmaxf(a[r][0], 0.f));
      Hbf[(size_t)(r0 + r) * HIDN + t + 256] = f2bf(fmaxf(a[r][1], 0.f));
    }
  }
}

// ---------------------------------------------------------------------------
// K2: dec[row] = sigmoid(H[rowobj[row]] @ W2^T + b2) for compact visible rows.
// W2 read directly as f32, converted to bf16 in-register (RNE, bit-identical
// to the old cvt path).  BK=64, 3-buffer depth-2 pipeline with counted
// vmcnt(6) + raw s_barrier so cold-HBM W2 latency hides under 2 phases.
// ---------------------------------------------------------------------------
__global__ __launch_bounds__(256) void k_gemm2_mfma(
    const unsigned short* __restrict__ Hbf,   // 540 x 512 bf16
    const float* __restrict__ W2,             // 512 x 12288 f32
    const float* __restrict__ b2,
    const int* __restrict__ nrowsp,
    const int* __restrict__ rowobj,
    float* __restrict__ dec)                  // 640 x 12288 f32 (compact rows)
{
  __shared__ unsigned short As[3][128 * BK];  // 3 x 16 KB, bf16, XOR-swizzled chunks
  __shared__ float          BsF[3][BK * 32];  // 3 x 8 KB, f32, [k][n] linear
  const int nr = *nrowsp;
  // XCD-aware bijective swizzle over the 1920-block grid (1920 = 8*240)
  int bid = (int)blockIdx.x;
  bid = (bid & 7) * 240 + (bid >> 3);
  const int m0 = (bid % 5) * 128;             // m fast -> active blocks spread
  if (m0 >= nr) return;
  const int n0 = (bid / 5) * 32;

  const int t    = threadIdx.x;
  const int lane = t & 63, wv = t >> 6;
  const int wm = (wv & 1) * 64;               // wave: 64 rows x 16 cols
  const int wn = (wv >> 1) * 16;

  // A staging: 1024 16B-chunks = 128 rows x 8 chunks; thread t stages chunks
  // c = i*256+t (i=0..3): row=c>>3, slot kk=c&7.  Dest is linear (gload_lds
  // rule); source pre-swizzled so LDS slot s of row holds logical chunk
  // s^(row&7)  ->  read addr row*8 + (lc^(row&7)).
  const int arow0 = t >> 3;
  const int kk    = t & 7;
  int ga_[4];
#pragma unroll
  for (int i = 0; i < 4; i++) {
    int row = i * 32 + arow0;
    ga_[i] = (m0 + row < nr) ? rowobj[m0 + row] : 0;   // tail rows -> row 0 (unread)
  }
  const unsigned short* aSrc[4];
#pragma unroll
  for (int i = 0; i < 4; i++) {
    int row = i * 32 + arow0;
    aSrc[i] = Hbf + (size_t)ga_[i] * HIDN + (kk ^ (row & 7)) * 8;
  }
  // B staging: 512 16B-chunks = 64 k x 8 n4; thread t stages c = i*256+t:
  // k = c>>3, n4 = c&7.  Linear both sides.
  const float* bSrc = W2 + (size_t)(t >> 3) * NOUT + n0 + (t & 7) * 4;

  const int fr = lane & 15;
  const int fj = lane >> 4;
  f32x4 acc[4] = {};

#define STAGE(buf, kt)                                                         \
  do {                                                                         \
    GLOAD_LDS16(aSrc[0] + (kt) * BK, &As[buf][(0 * 256 + t) * 8]);             \
    GLOAD_LDS16(aSrc[1] + (kt) * BK, &As[buf][(1 * 256 + t) * 8]);             \
    GLOAD_LDS16(aSrc[2] + (kt) * BK, &As[buf][(2 * 256 + t) * 8]);             \
    GLOAD_LDS16(aSrc[3] + (kt) * BK, &As[buf][(3 * 256 + t) * 8]);             \
    GLOAD_LDS16(bSrc + (size_t)((kt) * BK) * NOUT, &BsF[buf][t * 4]);          \
    GLOAD_LDS16(bSrc + (size_t)((kt) * BK + 32) * NOUT,                        \
                &BsF[buf][(256 + t) * 4]);                                     \
  } while (0)

  STAGE(0, 0);
  STAGE(1, 1);
#pragma unroll
  for (int kt = 0; kt < NK; ++kt) {
    // wait for phase-kt data: newest 6 loads (phase kt+1) may stay in flight
    if (kt + 1 < NK) asm volatile("s_waitcnt vmcnt(6)" ::: "memory");
    else             asm volatile("s_waitcnt vmcnt(0)" ::: "memory");
    __builtin_amdgcn_s_barrier();
    __builtin_amdgcn_sched_barrier(0);
    if (kt + 2 < NK) STAGE((kt + 2) % 3, kt + 2);   // WAR-safe after barrier
    const int bc = kt % 3;
#pragma unroll
    for (int ks = 0; ks < 2; ks++) {
      bf16x8 bv;
#pragma unroll
      for (int j = 0; j < 8; j++)
        bv[j] = (short)f2bf(BsF[bc][(ks * 32 + fj * 8 + j) * 32 + wn + fr]);
#pragma unroll
      for (int mi = 0; mi < 4; mi++) {
        int row = wm + mi * 16 + fr;
        int lc  = ks * 4 + fj;
        bf16x8 av = *(const bf16x8*)&As[bc][(row * 8 + (lc ^ (row & 7))) * 8];
        acc[mi] = __builtin_amdgcn_mfma_f32_16x16x32_bf16(av, bv, acc[mi], 0, 0, 0);
      }
    }
  }
#undef STAGE

  const int col = n0 + wn + fr;
  const float bb = b2[col];
#pragma unroll
  for (int mi = 0; mi < 4; mi++) {
#pragma unroll
    for (int r = 0; r < 4; r++) {
      int row = m0 + wm + mi * 16 + fj * 4 + r;   // < 640, dec has 640 rows
      float v = acc[mi][r] + bb;
      dec[(size_t)row * NOUT + col] = 1.0f / (1.0f + __expf(-v));
    }
  }
}

// ---------------------------------------------------------------------------
// K3: light composite — winner is precomputed; recompute its fp64 taps
// (bit-identical math) and gather 12 floats from the compact dec row.
// ---------------------------------------------------------------------------
__global__ __launch_bounds__(256) void k_composite(
    const int* __restrict__ pxwin, const int* __restrict__ remap,
    const float* __restrict__ z_where, const float* __restrict__ dec,
    float* __restrict__ out)
{
#pragma clang fp contract(off)
  const int bid  = blockIdx.x;
  const int t    = threadIdx.x;
  const int b    = bid >> 6;
  const int tile = bid & 63;
  const int y = (tile >> 3) * 16 + (t >> 4);
  const int x = (tile & 7) * 16 + (t & 15);

  const int win = pxwin[b * 16384 + y * 128 + x];
  float o0 = 0.f, o1 = 0.f, o2 = 0.f;
  if (win >= 0) {
    const F4 p = *(const F4*)&z_where[((size_t)b * NBOX + win) * 4];
    const double step = 2.0 / 127.0;
    const double gx = (x == 127) ? 1.0 : ((double)x * step + (-1.0));
    const double gy = (y == 127) ? 1.0 : ((double)y * step + (-1.0));
    double w = fmax((double)p.z, 0.01);
    double h = fmax((double)p.w, 0.01);
    double tx = 2.0 * (double)p.x - 1.0;
    double ty = 2.0 * (double)p.y - 1.0;
    double u = (gx - tx) / w;
    double v = (gy - ty) / h;
    double px = (u + 1.0) * 0.5 * 63.0;
    double py = (v + 1.0) * 0.5 * 63.0;
    double fx = floor(px), fy = floor(py);
    double wx = px - fx, wy = py - fy;
    int x0 = (int)fx, y0 = (int)fy;
    int x1 = x0 + 1, y1 = y0 + 1;
    bool vx0 = (x0 >= 0) && (x0 < OBJS);
    bool vx1 = (x1 >= 0) && (x1 < OBJS);
    bool vy0 = (y0 >= 0) && (y0 < OBJS);
    bool vy1 = (y1 >= 0) && (y1 < OBJS);
    double w00 = (1.0 - wy) * (1.0 - wx);
    double w01 = (1.0 - wy) * wx;
    double w10 = wy * (1.0 - wx);
    double w11 = wy * wx;
    bool c00 = vy0 && vx0 && (w00 > 0.0);
    bool c01 = vy0 && vx1 && (w01 > 0.0);
    bool c10 = vy1 && vx0 && (w10 > 0.0);
    bool c11 = vy1 && vx1 && (w11 > 0.0);
    const int row = remap[b * NOBJ + (win >> 2)];
    const float* g = dec + (size_t)row * NOUT;
    double s0 = 0.0, s1 = 0.0, s2 = 0.0;
    if (c00) { int o = y0*64 + x0; s0 += g[o]*w00; s1 += g[4096+o]*w00; s2 += g[8192+o]*w00; }
    if (c01) { int o = y0*64 + x1; s0 += g[o]*w01; s1 += g[4096+o]*w01; s2 += g[8192+o]*w01; }
    if (c10) { int o = y1*64 + x0; s0 += g[o]*w10; s1 += g[4096+o]*w10; s2 += g[8192+o]*w10; }
    if (c11) { int o = y1*64 + x1; s0 += g[o]*w11; s1 += g[4096+o]*w11; s2 += g[8192+o]*w11; }
    o0 = (float)s0; o1 = (float)s1; o2 = (float)s2;
  }
  const int ob = b * 3 * 16384 + y * 128 + x;    // (B,3,128,128)
  out[ob]         = o0;
  out[ob + 16384] = o1;
  out[ob + 32768] = o2;
}

// ---------------------------------------------------------------------------
extern "C" void kernel_launch(void* const* d_in, const int* in_sizes, int n_in,
                              void* d_out, int out_size, void* d_ws, size_t ws_size,
                              hipStream_t stream) {
  (void)in_sizes; (void)n_in; (void)out_size; (void)ws_size;
  const float* z_what    = (const float*)d_in[0];
  const float* z_where   = (const float*)d_in[1];
  const float* z_depth   = (const float*)d_in[2];
  const float* W1        = (const float*)d_in[3];
  const float* b1        = (const float*)d_in[4];
  const float* W2        = (const float*)d_in[5];
  const float* b2        = (const float*)d_in[6];
  const int*   z_present = (const int*)d_in[7];
  float* out = (float*)d_out;
  char* ws = (char*)d_ws;

  int*            nrowsp = (int*)(ws + OFF_NROWS);
  int*            used   = (int*)(ws + OFF_USED);
  int*            remap  = (int*)(ws + OFF_REMAP);
  int*            rowobj = (int*)(ws + OFF_ROWOBJ);
  int*            pxwin  = (int*)(ws + OFF_PXWIN);
  unsigned short* Hbf    = (unsigned short*)(ws + OFF_HBF);
  float*          dec    = (float*)(ws + OFF_DEC);

  // zero nrows + used[] (workspace is poisoned between iterations)
  hipMemsetAsync(ws + OFF_NROWS, 0, 2560, stream);

  k_pre<<<dim3(PRE_BLOCKS), dim3(256), 0, stream>>>(
      z_depth, z_where, z_present, z_what, W1, b1,
      nrowsp, used, remap, rowobj, pxwin, Hbf);
  k_gemm2_mfma<<<dim3(G2_BLOCKS), dim3(256), 0, stream>>>(
      Hbf, W2, b2, nrowsp, rowobj, dec);
  k_composite<<<dim3(256), dim3(256), 0, stream>>>(pxwin, remap, z_where, dec, out);
}

// Round 7
// 112.693 us; speedup vs baseline: 1.3417x; 1.0035x over previous
//
#include <hip/hip_runtime.h>
#include <hip/hip_bf16.h>
#include <math.h>

#define NBOX  540      // total boxes per batch
#define NOBJ  135      // unique objects per batch
#define ZW    64
#define HIDN  512
#define NOUT  12288    // 3*64*64
#define OBJS  64
#define BATCH 4

// fused K1 block roles: [winner 256 | gemm1 135 (4 rows/block)]
#define ROLE_WIN   256
#define ROLE_G1    135
#define PRE_BLOCKS (ROLE_WIN + ROLE_G1)

// gemm2 grid: 384 n-tiles (32 cols) x 5 m-tiles (128 rows), m is FAST dim so
// active (m0=0) blocks spread across XCDs under the swizzle.
#define G2_BLOCKS  1920
#define BK   64
#define NK   (HIDN / BK)     // 8 K-phases

// workspace layout (bytes), 256-aligned
#define OFF_NROWS  0u          // int
#define OFF_USED   256u        // int[540]   -> 2416
#define OFF_REMAP  2560u       // int[540]   -> 4720
#define OFF_ROWOBJ 4864u       // int[640]   -> 7424
#define OFF_PXWIN  7680u       // int[65536] -> 269824
#define OFF_HBF    269824u     // ushort 640*512 = 655360 -> 925184
#define OFF_DEC    13508096u   // float 640*12288 = 31457280 -> ~45 MB

typedef short  bf16x8 __attribute__((ext_vector_type(8)));
typedef float  f32x4  __attribute__((ext_vector_type(4)));

struct F4 { float x, y, z, w; };   // POD float4 (union-safe)

#define GLOAD_LDS16(gp, lp)                                                    \
  __builtin_amdgcn_global_load_lds(                                            \
      (const __attribute__((address_space(1))) void*)(gp),                     \
      (__attribute__((address_space(3))) void*)(lp), 16, 0, 0)

__device__ __forceinline__ unsigned short f2bf(float x) {
  __hip_bfloat16 h = __float2bfloat16(x);
  return *(unsigned short*)&h;
}

// ---------------------------------------------------------------------------
// K1: fused {painter visibility search | gemm1}
// Winner role: rank-sort (O(n^2), barrier-free) the batch's 135 depths,
// compact present boxes in depth order into LDS with conservative integer
// bboxes (wave-uniform skip) + f32 prefilter with exact fp64 fallback.
// All coverage decisions bit-identical to the reference predicate.
// ---------------------------------------------------------------------------
__global__ __launch_bounds__(256) void k_pre(
    const float* __restrict__ z_depth,   // B*135
    const float* __restrict__ z_where,   // B*540*4
    const int*   __restrict__ z_present, // B*540
    const float* __restrict__ Z,         // B*135*64 z_what
    const float* __restrict__ W1,        // 64*512
    const float* __restrict__ b1,        // 512
    int* __restrict__ nrowsp,            // compact visible-row count (pre-zeroed)
    int* __restrict__ used,              // int[540] (pre-zeroed)
    int* __restrict__ remap,             // (b*135+obj) -> compact row
    int* __restrict__ rowobj,            // compact row -> (b*135+obj)
    int* __restrict__ pxwin,             // per-pixel winning box (orig id) or -1
    unsigned short* __restrict__ Hbf)    // 540*512 bf16
{
  __shared__ union ShMem {
    struct {
      unsigned su[136];               // 544   orderable depth keys
      int      sobj[136];             // 544   rank -> obj
      F4       cf[NBOX];              // 8640  f32 {tx, ty, rx, ry} per candidate
      unsigned cbb[NBOX];             // 2160  packed bbox xlo|xhi|ylo|yhi
      int      cbx[NBOX];             // 2160  original box index
    } win;                            // ~14 KB
    float    zs[4][ZW];               // 1024  (gemm1 role, 4 rows)
  } u;
  __shared__ int wsums[4], woff[4], nPs;

  const int bid = blockIdx.x;
  const int t   = threadIdx.x;

  if (bid < ROLE_WIN) {
    // ---- role 0: visibility search ----
#pragma clang fp contract(off)
    const int b    = bid >> 6;
    const int tile = bid & 63;
    const int lane = t & 63, wv = t >> 6;
    const int y = (tile >> 3) * 16 + (t >> 4);
    const int x = (tile & 7) * 16 + (t & 15);

    // O(n^2) stable rank sort: asc by (~u, obj) == depth desc, ties obj asc
    if (t < NOBJ) {
      unsigned uu = __float_as_uint(z_depth[b * NOBJ + t]);
      uu = (uu & 0x80000000u) ? ~uu : (uu | 0x80000000u);     // orderable uint
      u.win.su[t] = uu;
    }
    __syncthreads();
    if (t < NOBJ) {
      const unsigned mykey = u.win.su[t];
      int r = 0;
      for (int j = 0; j < NOBJ; j++) {
        unsigned kj = u.win.su[j];
        r += (int)((kj > mykey) || (kj == mykey && j < t));
      }
      u.win.sobj[r] = t;
    }
    __syncthreads();

    // compact present boxes (sorted order) + bboxes + f32 prefilter params
    int boxq[3], presq[3], cnt = 0;
#pragma unroll
    for (int q = 0; q < 3; q++) {
      int e = 3 * t + q;
      presq[q] = 0; boxq[q] = 0;
      if (e < NBOX) {
        int o  = u.win.sobj[e >> 2];
        int bx = o * 4 + (e & 3);
        boxq[q]  = bx;
        presq[q] = (z_present[b * NBOX + bx] != 0) ? 1 : 0;
        cnt += presq[q];
      }
    }
    int incl = cnt;
#pragma unroll
    for (int o = 1; o < 64; o <<= 1) {
      int vprev = __shfl_up(incl, o, 64);
      if (lane >= o) incl += vprev;
    }
    if (lane == 63) wsums[wv] = incl;
    __syncthreads();
    if (t == 0) {
      int a = 0;
#pragma unroll
      for (int i = 0; i < 4; i++) { woff[i] = a; a += wsums[i]; }
      nPs = a;
    }
    __syncthreads();
    int slot = woff[wv] + incl - cnt;
#pragma unroll
    for (int q = 0; q < 3; q++) {
      if (presq[q]) {
        int bx = boxq[q];
        F4 p = *(const F4*)&z_where[((size_t)b * NBOX + bx) * 4];
        double w  = fmax((double)p.z, 0.01);
        double h  = fmax((double)p.w, 0.01);
        double tx = 2.0 * (double)p.x - 1.0;
        double ty = 2.0 * (double)p.y - 1.0;
        const double S = 65.0 / 63.0;       // coverage iff |gx-tx| < w*S (real)
        int xlo = (int)floor((tx - w * S + 1.0) * 63.5) - 1;   // 63.5 = 1/step
        int xhi = (int)floor((tx + w * S + 1.0) * 63.5) + 2;
        int ylo = (int)floor((ty - h * S + 1.0) * 63.5) - 1;
        int yhi = (int)floor((ty + h * S + 1.0) * 63.5) + 2;
        xlo = max(xlo, 0); ylo = max(ylo, 0);
        xhi = min(xhi, 127); yhi = min(yhi, 127);
        unsigned bb = (xhi < xlo || yhi < ylo) ? 0xFFu   // sentinel: always skip
                    : ((unsigned)xlo | ((unsigned)xhi << 8) |
                       ((unsigned)ylo << 16) | ((unsigned)yhi << 24));
        F4 f;
        f.x = (float)tx; f.y = (float)ty;
        f.z = (float)(w * S); f.w = (float)(h * S);
        u.win.cf[slot]  = f;
        u.win.cbb[slot] = bb;
        u.win.cbx[slot] = bx;
        slot++;
      }
    }
    __syncthreads();

    const int nP = nPs;
    const double step = 2.0 / 127.0;
    const double gx = (x == 127) ? 1.0 : ((double)x * step + (-1.0));
    const double gy = (y == 127) ? 1.0 : ((double)y * step + (-1.0));
    const float gxf = (float)gx, gyf = (float)gy;
    const int tx0 = (tile & 7) * 16, tx1 = tx0 + 15;
    const int wy0 = (tile >> 3) * 16 + wv * 4, wy1 = wy0 + 3;  // wave's 16x4 strip

    bool done = false;
    int  win  = -1;
    for (int j = 0; j < nP; j++) {
      if (__all((int)done)) break;
      unsigned bb = u.win.cbb[j];
      int bxlo = (int)(bb & 255u),         bxhi = (int)((bb >> 8) & 255u);
      int bylo = (int)((bb >> 16) & 255u), byhi = (int)(bb >> 24);
      if (bxhi < tx0 || bxlo > tx1 || byhi < wy0 || bylo > wy1) continue;
      bool newly = false;
      if (!done) {
        F4 f = u.win.cf[j];
        float dx = fabsf(gxf - f.x), dy = fabsf(gyf - f.y);
        // conservative margins: f32 pipeline error <= ~5e-7, band = 1e-4 rel + 2e-6 abs
        bool in_lo = (dx < f.z * 0.9999f - 2e-6f) & (dy < f.w * 0.9999f - 2e-6f);
        bool in_hi = (dx < f.z * 1.0001f + 2e-6f) & (dy < f.w * 1.0001f + 2e-6f);
        bool cov;
        if (in_lo) {
          cov = true;                       // definitely covered
        } else if (!in_hi) {
          cov = false;                      // definitely not covered
        } else {
          // borderline (~1e-4 prob): exact fp64 sequence, bit-identical to ref
          F4 p = *(const F4*)&z_where[((size_t)b * NBOX + u.win.cbx[j]) * 4];
          double w  = fmax((double)p.z, 0.01);
          double h  = fmax((double)p.w, 0.01);
          double tx = 2.0 * (double)p.x - 1.0;
          double ty = 2.0 * (double)p.y - 1.0;
          double uu = (gx - tx) / w;
          double vv = (gy - ty) / h;
          double px = (uu + 1.0) * 0.5 * 63.0;
          double py = (vv + 1.0) * 0.5 * 63.0;
          cov = (px > -1.0) && (px < 64.0) && (py > -1.0) && (py < 64.0);
        }
        if (cov) { win = u.win.cbx[j]; done = true; newly = true; }
      }
      unsigned long long nm = __ballot((int)newly);
      if (nm != 0ull && lane == (int)__builtin_ctzll(nm)) {
        int oi = b * NOBJ + (win >> 2);     // this lane is newly => win = cbx[j]
        if (atomicCAS(&used[oi], 0, 1) == 0) {
          int rr = atomicAdd(nrowsp, 1);
          rowobj[rr] = oi;
          remap[oi]  = rr;
        }
      }
    }
    pxwin[b * 16384 + y * 128 + x] = win;
  } else {
    // ---- role 1: H[r] = relu(Z[r] @ W1 + b1) -> bf16, 4 rows per block ----
    const int r0 = (bid - ROLE_WIN) * 4;     // rows r0..r0+3 (= b*135 + obj)
    u.zs[t >> 6][t & 63] = Z[(size_t)(r0 + (t >> 6)) * ZW + (t & 63)];
    __syncthreads();
    float a[4][2];
#pragma unroll
    for (int r = 0; r < 4; r++) { a[r][0] = b1[t]; a[r][1] = b1[t + 256]; }
#pragma unroll
    for (int k4 = 0; k4 < 16; k4++) {
      float4 zq[4];
#pragma unroll
      for (int r = 0; r < 4; r++) zq[r] = *(const float4*)&u.zs[r][k4 * 4];
#pragma unroll
      for (int kk = 0; kk < 4; kk++) {
        int k = k4 * 4 + kk;
        float w0 = W1[(size_t)k * HIDN + t];
        float w1 = W1[(size_t)k * HIDN + t + 256];
#pragma unroll
        for (int r = 0; r < 4; r++) {
          float z = ((const float*)&zq[r])[kk];
          a[r][0] += z * w0;
          a[r][1] += z * w1;
        }
      }
    }
#pragma unroll
    for (int r = 0; r < 4; r++) {
      Hbf[(size_t)(r0 + r) * HIDN + t]       = f2bf(fmaxf(a[r][0], 0.f));
      Hbf[(size_t)(r0 + r) * HIDN + t + 256] = f2bf(fmaxf(a[r][1], 0.f));
    }
  }
}

// ---------------------------------------------------------------------------
// K2: dec[row] = sigmoid(H[rowobj[row]] @ W2^T + b2) for compact visible rows.
// W2 read directly as f32, converted to bf16 in-register (RNE, bit-identical
// to the old cvt path).  BK=64, 3-buffer depth-2 pipeline with counted
// vmcnt(6) + raw s_barrier so cold-HBM W2 latency hides under 2 phases.
// ---------------------------------------------------------------------------
__global__ __launch_bounds__(256) void k_gemm2_mfma(
    const unsigned short* __restrict__ Hbf,   // 540 x 512 bf16
    const float* __restrict__ W2,             // 512 x 12288 f32
    const float* __restrict__ b2,
    const int* __restrict__ nrowsp,
    const int* __restrict__ rowobj,
    float* __restrict__ dec)                  // 640 x 12288 f32 (compact rows)
{
  __shared__ unsigned short As[3][128 * BK];  // 3 x 16 KB, bf16, XOR-swizzled chunks
  __shared__ float          BsF[3][BK * 32];  // 3 x 8 KB, f32, [k][n] linear
  const int nr = *nrowsp;
  // XCD-aware bijective swizzle over the 1920-block grid (1920 = 8*240)
  int bid = (int)blockIdx.x;
  bid = (bid & 7) * 240 + (bid >> 3);
  const int m0 = (bid % 5) * 128;             // m fast -> active blocks spread
  if (m0 >= nr) return;
  const int n0 = (bid / 5) * 32;

  const int t    = threadIdx.x;
  const int lane = t & 63, wv = t >> 6;
  const int wm = (wv & 1) * 64;               // wave: 64 rows x 16 cols
  const int wn = (wv >> 1) * 16;

  // A staging: 1024 16B-chunks = 128 rows x 8 chunks; thread t stages chunks
  // c = i*256+t (i=0..3): row=c>>3, slot kk=c&7.  Dest is linear (gload_lds
  // rule); source pre-swizzled so LDS slot s of row holds logical chunk
  // s^(row&7)  ->  read addr row*8 + (lc^(row&7)).
  const int arow0 = t >> 3;
  const int kk    = t & 7;
  int ga_[4];
#pragma unroll
  for (int i = 0; i < 4; i++) {
    int row = i * 32 + arow0;
    ga_[i] = (m0 + row < nr) ? rowobj[m0 + row] : 0;   // tail rows -> row 0 (unread)
  }
  const unsigned short* aSrc[4];
#pragma unroll
  for (int i = 0; i < 4; i++) {
    int row = i * 32 + arow0;
    aSrc[i] = Hbf + (size_t)ga_[i] * HIDN + (kk ^ (row & 7)) * 8;
  }
  // B staging: 512 16B-chunks = 64 k x 8 n4; thread t stages c = i*256+t:
  // k = c>>3, n4 = c&7.  Linear both sides.
  const float* bSrc = W2 + (size_t)(t >> 3) * NOUT + n0 + (t & 7) * 4;

  const int fr = lane & 15;
  const int fj = lane >> 4;
  f32x4 acc[4] = {};

#define STAGE(buf, kt)                                                         \
  do {                                                                         \
    GLOAD_LDS16(aSrc[0] + (kt) * BK, &As[buf][(0 * 256 + t) * 8]);             \
    GLOAD_LDS16(aSrc[1] + (kt) * BK, &As[buf][(1 * 256 + t) * 8]);             \
    GLOAD_LDS16(aSrc[2] + (kt) * BK, &As[buf][(2 * 256 + t) * 8]);             \
    GLOAD_LDS16(aSrc[3] + (kt) * BK, &As[buf][(3 * 256 + t) * 8]);             \
    GLOAD_LDS16(bSrc + (size_t)((kt) * BK) * NOUT, &BsF[buf][t * 4]);          \
    GLOAD_LDS16(bSrc + (size_t)((kt) * BK + 32) * NOUT,                        \
                &BsF[buf][(256 + t) * 4]);                                     \
  } while (0)

  STAGE(0, 0);
  STAGE(1, 1);
#pragma unroll
  for (int kt = 0; kt < NK; ++kt) {
    // wait for phase-kt data: newest 6 loads (phase kt+1) may stay in flight
    if (kt + 1 < NK) asm volatile("s_waitcnt vmcnt(6)" ::: "memory");
    else             asm volatile("s_waitcnt vmcnt(0)" ::: "memory");
    __builtin_amdgcn_s_barrier();
    __builtin_amdgcn_sched_barrier(0);
    if (kt + 2 < NK) STAGE((kt + 2) % 3, kt + 2);   // WAR-safe after barrier
    const int bc = kt % 3;
#pragma unroll
    for (int ks = 0; ks < 2; ks++) {
      bf16x8 bv;
#pragma unroll
      for (int j = 0; j < 8; j++)
        bv[j] = (short)f2bf(BsF[bc][(ks * 32 + fj * 8 + j) * 32 + wn + fr]);
#pragma unroll
      for (int mi = 0; mi < 4; mi++) {
        int row = wm + mi * 16 + fr;
        int lc  = ks * 4 + fj;
        bf16x8 av = *(const bf16x8*)&As[bc][(row * 8 + (lc ^ (row & 7))) * 8];
        acc[mi] = __builtin_amdgcn_mfma_f32_16x16x32_bf16(av, bv, acc[mi], 0, 0, 0);
      }
    }
  }
#undef STAGE

  const int col = n0 + wn + fr;
  const float bb = b2[col];
#pragma unroll
  for (int mi = 0; mi < 4; mi++) {
#pragma unroll
    for (int r = 0; r < 4; r++) {
      int row = m0 + wm + mi * 16 + fj * 4 + r;   // < 640, dec has 640 rows
      float v = acc[mi][r] + bb;
      dec[(size_t)row * NOUT + col] = 1.0f / (1.0f + __expf(-v));
    }
  }
}

// ---------------------------------------------------------------------------
// K3: light composite — winner is precomputed; recompute its fp64 taps
// (bit-identical math) and gather 12 floats from the compact dec row.
// ---------------------------------------------------------------------------
__global__ __launch_bounds__(256) void k_composite(
    const int* __restrict__ pxwin, const int* __restrict__ remap,
    const float* __restrict__ z_where, const float* __restrict__ dec,
    float* __restrict__ out)
{
#pragma clang fp contract(off)
  const int bid  = blockIdx.x;
  const int t    = threadIdx.x;
  const int b    = bid >> 6;
  const int tile = bid & 63;
  const int y = (tile >> 3) * 16 + (t >> 4);
  const int x = (tile & 7) * 16 + (t & 15);

  const int win = pxwin[b * 16384 + y * 128 + x];
  float o0 = 0.f, o1 = 0.f, o2 = 0.f;
  if (win >= 0) {
    const F4 p = *(const F4*)&z_where[((size_t)b * NBOX + win) * 4];
    const double step = 2.0 / 127.0;
    const double gx = (x == 127) ? 1.0 : ((double)x * step + (-1.0));
    const double gy = (y == 127) ? 1.0 : ((double)y * step + (-1.0));
    double w = fmax((double)p.z, 0.01);
    double h = fmax((double)p.w, 0.01);
    double tx = 2.0 * (double)p.x - 1.0;
    double ty = 2.0 * (double)p.y - 1.0;
    double u = (gx - tx) / w;
    double v = (gy - ty) / h;
    double px = (u + 1.0) * 0.5 * 63.0;
    double py = (v + 1.0) * 0.5 * 63.0;
    double fx = floor(px), fy = floor(py);
    double wx = px - fx, wy = py - fy;
    int x0 = (int)fx, y0 = (int)fy;
    int x1 = x0 + 1, y1 = y0 + 1;
    bool vx0 = (x0 >= 0) && (x0 < OBJS);
    bool vx1 = (x1 >= 0) && (x1 < OBJS);
    bool vy0 = (y0 >= 0) && (y0 < OBJS);
    bool vy1 = (y1 >= 0) && (y1 < OBJS);
    double w00 = (1.0 - wy) * (1.0 - wx);
    double w01 = (1.0 - wy) * wx;
    double w10 = wy * (1.0 - wx);
    double w11 = wy * wx;
    bool c00 = vy0 && vx0 && (w00 > 0.0);
    bool c01 = vy0 && vx1 && (w01 > 0.0);
    bool c10 = vy1 && vx0 && (w10 > 0.0);
    bool c11 = vy1 && vx1 && (w11 > 0.0);
    const int row = remap[b * NOBJ + (win >> 2)];
    const float* g = dec + (size_t)row * NOUT;
    double s0 = 0.0, s1 = 0.0, s2 = 0.0;
    if (c00) { int o = y0*64 + x0; s0 += g[o]*w00; s1 += g[4096+o]*w00; s2 += g[8192+o]*w00; }
    if (c01) { int o = y0*64 + x1; s0 += g[o]*w01; s1 += g[4096+o]*w01; s2 += g[8192+o]*w01; }
    if (c10) { int o = y1*64 + x0; s0 += g[o]*w10; s1 += g[4096+o]*w10; s2 += g[8192+o]*w10; }
    if (c11) { int o = y1*64 + x1; s0 += g[o]*w11; s1 += g[4096+o]*w11; s2 += g[8192+o]*w11; }
    o0 = (float)s0; o1 = (float)s1; o2 = (float)s2;
  }
  const int ob = b * 3 * 16384 + y * 128 + x;    // (B,3,128,128)
  out[ob]         = o0;
  out[ob + 16384] = o1;
  out[ob + 32768] = o2;
}

// ---------------------------------------------------------------------------
extern "C" void kernel_launch(void* const* d_in, const int* in_sizes, int n_in,
                              void* d_out, int out_size, void* d_ws, size_t ws_size,
                              hipStream_t stream) {
  (void)in_sizes; (void)n_in; (void)out_size; (void)ws_size;
  const float* z_what    = (const float*)d_in[0];
  const float* z_where   = (const float*)d_in[1];
  const float* z_depth   = (const float*)d_in[2];
  const float* W1        = (const float*)d_in[3];
  const float* b1        = (const float*)d_in[4];
  const float* W2        = (const float*)d_in[5];
  const float* b2        = (const float*)d_in[6];
  const int*   z_present = (const int*)d_in[7];
  float* out = (float*)d_out;
  char* ws = (char*)d_ws;

  int*            nrowsp = (int*)(ws + OFF_NROWS);
  int*            used   = (int*)(ws + OFF_USED);
  int*            remap  = (int*)(ws + OFF_REMAP);
  int*            rowobj = (int*)(ws + OFF_ROWOBJ);
  int*            pxwin  = (int*)(ws + OFF_PXWIN);
  unsigned short* Hbf    = (unsigned short*)(ws + OFF_HBF);
  float*          dec    = (float*)(ws + OFF_DEC);

  // zero nrows + used[] (workspace is poisoned between iterations)
  hipMemsetAsync(ws + OFF_NROWS, 0, 2560, stream);

  k_pre<<<dim3(PRE_BLOCKS), dim3(256), 0, stream>>>(
      z_depth, z_where, z_present, z_what, W1, b1,
      nrowsp, used, remap, rowobj, pxwin, Hbf);
  k_gemm2_mfma<<<dim3(G2_BLOCKS), dim3(256), 0, stream>>>(
      Hbf, W2, b2, nrowsp, rowobj, dec);
  k_composite<<<dim3(256), dim3(256), 0, stream>>>(pxwin, remap, z_where, dec, out);
}